// Round 1
// baseline (2795.481 us; speedup 1.0000x reference)
//
#include <hip/hip_runtime.h>
#include <hip/hip_bf16.h>

typedef __hip_bfloat16 bf16;

#define Bsz 512
#define S3  512
#define Tsz 16
#define Cc  128
#define TT  15
#define EPSv 1e-5f

__device__ __forceinline__ float u2f(unsigned short u) {
    return __uint_as_float(((unsigned)u) << 16);
}
__device__ __forceinline__ float b2f(bf16 v) { return __bfloat162float(v); }
__device__ __forceinline__ bf16  f2b(float v) { return __float2bfloat16(v); }

// ---------------------------------------------------------------------------
// k_init: features -> lin_in -> x0 (bf16), mask, n->inv, s0 (masked sum)
// one block per batch element
// ---------------------------------------------------------------------------
__global__ __launch_bounds__(256) void k_init(
    const int* __restrict__ xx, const float* __restrict__ ss,
    const float* __restrict__ Win, const float* __restrict__ b_in,
    bf16* __restrict__ xbuf, float* __restrict__ sbuf,
    float* __restrict__ invbuf, float* __restrict__ mbuf)
{
    int b = blockIdx.x, tid = threadIdx.x;
    int co = tid & 127, g = tid >> 7;   // g in {0,1}
    const int* x0 = xx + (size_t)b * Tsz * S3;   // frame 0
    float ssb = ss[b];
    float f4c = ssb * (1.0f / 8.0f);
    float w0 = Win[co * 5 + 0], w1 = Win[co * 5 + 1], w2 = Win[co * 5 + 2];
    float w3 = Win[co * 5 + 3], w4 = Win[co * 5 + 4];
    float bb = b_in[co];

    __shared__ float sred[256];
    __shared__ float scnt[2];

    float spart = 0.f; int cnt = 0;
    for (int node = g; node < S3; node += 2) {
        int f0 = x0[node];
        float m = (f0 != 0) ? 1.f : 0.f;
        float ci = (float)(node >> 6) * (1.f / 7.f);
        float cj = (float)((node >> 3) & 7) * (1.f / 7.f);
        float ck = (float)(node & 7) * (1.f / 7.f);
        float v = bb + ci * w0 + cj * w1 + ck * w2 + ((float)f0 * 0.5f) * w3 + f4c * w4;
        xbuf[(size_t)(b * S3 + node) * Cc + co] = f2b(v);
        spart += v * m;
        cnt += (f0 != 0);
        if (co == 0) mbuf[b * S3 + node] = m;
    }
    sred[tid] = spart;
    if (tid == 0)   scnt[0] = (float)cnt;
    if (tid == 128) scnt[1] = (float)cnt;
    __syncthreads();
    if (g == 0) sbuf[b * Cc + co] = spart + sred[128 + co];
    if (tid == 0) {
        float n = scnt[0] + scnt[1];
        invbuf[b] = (n > 1.f) ? 1.f / (n - 1.f) : 0.f;
    }
}

// ---------------------------------------------------------------------------
// k_gnn: one SAGE layer, in-place update of x (bf16).
//   h[n][c] = base[c] + sum_k x[n][k] * (Wr[c][k] - inv*Wl[c][k])
//   base[c] = bl[c] + sum_k (s[k]*inv) * Wl[c][k]
//   x <- LN(relu(h)); accumulate next masked sum into sout (atomics)
// grid = B * 8 tiles of 64 nodes; block = 256 (thread = 2 c_out x 16 nodes)
// ---------------------------------------------------------------------------
__global__ __launch_bounds__(256) void k_gnn(
    bf16* __restrict__ xbuf,
    const float* __restrict__ sIn, const float* __restrict__ invbuf,
    const float* __restrict__ Wl, const float* __restrict__ blv,
    const float* __restrict__ Wr,
    const float* __restrict__ lng, const float* __restrict__ lnb,
    const float* __restrict__ mbuf,
    float* __restrict__ sout, int acc_s)
{
    __shared__ float smem[64 * 129];   // x phase: stride 128 (8192), h phase: stride 129
    __shared__ float sinv[128];
    __shared__ float stats[128];       // mu[0:64], rstd[64:128]
    __shared__ float sred[512];

    int tid = threadIdx.x;
    int b = blockIdx.x >> 3;
    int node0 = (blockIdx.x & 7) * 64;
    float inv = invbuf[b];

    // load x tile (64 nodes x 128 ch, bf16) -> fp32 LDS stride 128
    const ushort4* xg4 = (const ushort4*)(xbuf + (size_t)(b * S3 + node0) * Cc);
    for (int f = tid; f < 2048; f += 256) {
        ushort4 u = xg4[f];
        float4 v;
        v.x = u2f(u.x); v.y = u2f(u.y); v.z = u2f(u.z); v.w = u2f(u.w);
        ((float4*)smem)[f] = v;
    }
    if (tid < 128) sinv[tid] = sIn[b * Cc + tid] * inv;
    __syncthreads();

    int co0 = tid & 63;
    int co1 = co0 + 64;
    int g = tid >> 6;                  // 0..3 -> 16 nodes each
    const float* wl0 = Wl + co0 * Cc;
    const float* wl1 = Wl + co1 * Cc;
    const float* wr0 = Wr + co0 * Cc;
    const float* wr1 = Wr + co1 * Cc;

    float acc0[16], acc1[16];
#pragma unroll
    for (int i = 0; i < 16; i++) { acc0[i] = 0.f; acc1[i] = 0.f; }
    float base0 = blv[co0], base1 = blv[co1];

    for (int k = 0; k < Cc; k += 4) {
        float4 a0 = *(const float4*)(wl0 + k);
        float4 a1 = *(const float4*)(wl1 + k);
        float4 r0 = *(const float4*)(wr0 + k);
        float4 r1 = *(const float4*)(wr1 + k);
        float4 sv = *(const float4*)(sinv + k);
        base0 += sv.x * a0.x + sv.y * a0.y + sv.z * a0.z + sv.w * a0.w;
        base1 += sv.x * a1.x + sv.y * a1.y + sv.z * a1.z + sv.w * a1.w;
        float4 c0, c1;
        c0.x = r0.x - inv * a0.x; c0.y = r0.y - inv * a0.y;
        c0.z = r0.z - inv * a0.z; c0.w = r0.w - inv * a0.w;
        c1.x = r1.x - inv * a1.x; c1.y = r1.y - inv * a1.y;
        c1.z = r1.z - inv * a1.z; c1.w = r1.w - inv * a1.w;
        const float* xs = smem + (g * 16) * Cc + k;
#pragma unroll
        for (int i = 0; i < 16; i++) {
            float4 xv = *(const float4*)(xs + i * Cc);   // broadcast read
            acc0[i] += xv.x * c0.x + xv.y * c0.y + xv.z * c0.z + xv.w * c0.w;
            acc1[i] += xv.x * c1.x + xv.y * c1.y + xv.z * c1.z + xv.w * c1.w;
        }
    }
    __syncthreads();   // x tile dead; reuse smem (stride 129) for h

#pragma unroll
    for (int i = 0; i < 16; i++) {
        int node = g * 16 + i;
        smem[node * 129 + co0] = fmaxf(acc0[i] + base0, 0.f);
        smem[node * 129 + co1] = fmaxf(acc1[i] + base1, 0.f);
    }
    __syncthreads();

    if (tid < 64) {
        const float* row = smem + tid * 129;
        float s = 0.f, s2 = 0.f;
        for (int j = 0; j < 128; j++) { float v = row[j]; s += v; s2 += v * v; }
        float mu = s * (1.f / 128.f);
        float var = s2 * (1.f / 128.f) - mu * mu;
        stats[tid] = mu;
        stats[64 + tid] = rsqrtf(var + EPSv);
    }
    __syncthreads();

    float gg0 = lng[co0], gg1 = lng[co1], be0 = lnb[co0], be1 = lnb[co1];
    float sp0 = 0.f, sp1 = 0.f;
    bf16* xo = xbuf + (size_t)(b * S3 + node0) * Cc;
#pragma unroll
    for (int i = 0; i < 16; i++) {
        int node = g * 16 + i;
        float mu = stats[node], rs = stats[64 + node];
        float y0 = (smem[node * 129 + co0] - mu) * rs * gg0 + be0;
        float y1 = (smem[node * 129 + co1] - mu) * rs * gg1 + be1;
        xo[node * Cc + co0] = f2b(y0);
        xo[node * Cc + co1] = f2b(y1);
        float m = mbuf[b * S3 + node0 + node];
        sp0 += y0 * m;
        sp1 += y1 * m;
    }
    if (acc_s) {
        sred[g * 128 + co0] = sp0;
        sred[g * 128 + co1] = sp1;
        __syncthreads();
        if (tid < 128) {
            float t = sred[tid] + sred[128 + tid] + sred[256 + tid] + sred[384 + tid];
            atomicAdd(&sout[b * Cc + tid], t);
        }
    }
}

// ---------------------------------------------------------------------------
// k_pool: gnn_emb = slice means of (x * m) -> out[b][0..23][c]
// ---------------------------------------------------------------------------
__global__ __launch_bounds__(256) void k_pool(
    const bf16* __restrict__ xbuf, const float* __restrict__ mbuf,
    float* __restrict__ out)
{
    int b = blockIdx.x, tid = threadIdx.x;
    for (int f = tid; f < 24 * 128; f += 256) {
        int p = f >> 7, c = f & 127;
        int axis = p >> 3, idx = p & 7;
        float sum = 0.f;
        for (int t = 0; t < 64; t++) {
            int node;
            if (axis == 0)      node = idx * 64 + t;
            else if (axis == 1) node = (t >> 3) * 64 + idx * 8 + (t & 7);
            else                node = t * 8 + idx;
            sum += b2f(xbuf[(size_t)(b * S3 + node) * Cc + c]) * mbuf[b * S3 + node];
        }
        out[(size_t)b * 26 * Cc + p * Cc + c] = sum * (1.f / 64.f);
    }
}

// ---------------------------------------------------------------------------
// k_tf: action embed + 2 pre-LN transformer layers + act_emb + mv_emb,
// entirely in LDS. One block (256 thr) per batch element.
// ---------------------------------------------------------------------------
__global__ __launch_bounds__(256) void k_tf(
    const int* __restrict__ xx, const float* __restrict__ ss,
    const float* __restrict__ Wqkv, const float* __restrict__ bqkv,
    const float* __restrict__ Wo, const float* __restrict__ bo,
    const float* __restrict__ ln1g, const float* __restrict__ ln1b,
    const float* __restrict__ ln2g, const float* __restrict__ ln2b,
    const float* __restrict__ W1, const float* __restrict__ b1,
    const float* __restrict__ W2, const float* __restrict__ b2,
    const float* __restrict__ Wact, const float* __restrict__ bact,
    const float* __restrict__ Wsc, const float* __restrict__ bsc,
    float* __restrict__ out)
{
    __shared__ float a_s[TT * 132];
    __shared__ float sc1[TT * 132];
    __shared__ float big[TT * 516];   // xx-stage / ff (stride 516), qkv (stride 384)
    __shared__ float att[60 * 16];
    __shared__ float mu_s[16], rs_s[16];

    int b = blockIdx.x, tid = threadIdx.x;

    // stage xx[:,1:] as float (stride 516)
    const int* xa = xx + (size_t)b * Tsz * S3 + S3;
    for (int f = tid; f < TT * 512; f += 256) {
        int t = f >> 9, s = f & 511;
        big[t * 516 + s] = (float)xa[t * 512 + s];
    }
    __syncthreads();

    // a = v @ Wact^T + bact
    for (int f = tid; f < TT * 128; f += 256) {
        int t = f >> 7, co = f & 127;
        const float* wrow = Wact + co * 512;
        const float* vrow = big + t * 516;
        float acc = bact[co];
        for (int s = 0; s < 512; s += 4) {
            float4 v4 = *(const float4*)(vrow + s);
            float4 w4 = *(const float4*)(wrow + s);
            acc += v4.x * w4.x + v4.y * w4.y + v4.z * w4.z + v4.w * w4.w;
        }
        a_s[t * 132 + co] = acc;
    }
    __syncthreads();

    for (int l = 0; l < 2; l++) {
        const float* Wq  = Wqkv + (size_t)l * 384 * 128;
        const float* bq  = bqkv + l * 384;
        const float* Wol = Wo + (size_t)l * 128 * 128;
        const float* bol = bo + l * 128;
        const float* g1  = ln1g + l * 128; const float* be1 = ln1b + l * 128;
        const float* g2  = ln2g + l * 128; const float* be2 = ln2b + l * 128;
        const float* W1l = W1 + (size_t)l * 512 * 128; const float* b1l = b1 + l * 512;
        const float* W2l = W2 + (size_t)l * 128 * 512; const float* b2l = b2 + l * 128;

        // ----- LN1
        if (tid < TT) {
            const float* row = a_s + tid * 132;
            float s = 0.f, s2 = 0.f;
            for (int j = 0; j < 128; j++) { float v = row[j]; s += v; s2 += v * v; }
            float mu = s * (1.f / 128.f);
            mu_s[tid] = mu;
            rs_s[tid] = rsqrtf(s2 * (1.f / 128.f) - mu * mu + EPSv);
        }
        __syncthreads();
        for (int f = tid; f < TT * 128; f += 256) {
            int t = f >> 7, co = f & 127;
            sc1[t * 132 + co] = (a_s[t * 132 + co] - mu_s[t]) * rs_s[t] * g1[co] + be1[co];
        }
        __syncthreads();

        // ----- qkv (into big, stride 384)
        for (int f = tid; f < TT * 384; f += 256) {
            int t = f / 384, co = f % 384;
            const float* wrow = Wq + co * 128;
            const float* hrow = sc1 + t * 132;
            float acc = bq[co];
            for (int k = 0; k < 128; k += 4) {
                float4 h4 = *(const float4*)(hrow + k);
                float4 w4 = *(const float4*)(wrow + k);
                acc += h4.x * w4.x + h4.y * w4.y + h4.z * w4.z + h4.w * w4.w;
            }
            big[t * 384 + co] = acc;
        }
        __syncthreads();

        // ----- scores + softmax (thread = (head, tq))
        if (tid < 60) {
            int h = tid / 15, tq = tid % 15;
            const float* qp = big + tq * 384 + h * 32;
            float sc[TT];
            float mx = -1e30f;
#pragma unroll
            for (int tk = 0; tk < TT; tk++) {
                const float* kp = big + tk * 384 + 128 + h * 32;
                float d = 0.f;
#pragma unroll
                for (int u = 0; u < 32; u += 4) {
                    float4 q4 = *(const float4*)(qp + u);
                    float4 k4 = *(const float4*)(kp + u);
                    d += q4.x * k4.x + q4.y * k4.y + q4.z * k4.z + q4.w * k4.w;
                }
                d *= 0.17677669529663689f;   // 1/sqrt(32)
                sc[tk] = d; mx = fmaxf(mx, d);
            }
            float sum = 0.f;
#pragma unroll
            for (int tk = 0; tk < TT; tk++) { float e = expf(sc[tk] - mx); sc[tk] = e; sum += e; }
            float r = 1.f / sum;
#pragma unroll
            for (int tk = 0; tk < TT; tk++) att[tid * 16 + tk] = sc[tk] * r;
        }
        __syncthreads();

        // ----- o = att @ v  -> sc1
        for (int f = tid; f < TT * 128; f += 256) {
            int t = f >> 7, co = f & 127;
            int h = co >> 5;
            const float* ap = att + (h * 15 + t) * 16;
            const float* vp = big + 256 + co;
            float acc = 0.f;
#pragma unroll
            for (int tk = 0; tk < TT; tk++) acc += ap[tk] * vp[tk * 384];
            sc1[t * 132 + co] = acc;
        }
        __syncthreads();

        // ----- proj + residual
        for (int f = tid; f < TT * 128; f += 256) {
            int t = f >> 7, co = f & 127;
            const float* wrow = Wol + co * 128;
            const float* orow = sc1 + t * 132;
            float acc = bol[co];
            for (int k = 0; k < 128; k += 4) {
                float4 o4 = *(const float4*)(orow + k);
                float4 w4 = *(const float4*)(wrow + k);
                acc += o4.x * w4.x + o4.y * w4.y + o4.z * w4.z + o4.w * w4.w;
            }
            a_s[t * 132 + co] += acc;
        }
        __syncthreads();

        // ----- LN2
        if (tid < TT) {
            const float* row = a_s + tid * 132;
            float s = 0.f, s2 = 0.f;
            for (int j = 0; j < 128; j++) { float v = row[j]; s += v; s2 += v * v; }
            float mu = s * (1.f / 128.f);
            mu_s[tid] = mu;
            rs_s[tid] = rsqrtf(s2 * (1.f / 128.f) - mu * mu + EPSv);
        }
        __syncthreads();
        for (int f = tid; f < TT * 128; f += 256) {
            int t = f >> 7, co = f & 127;
            sc1[t * 132 + co] = (a_s[t * 132 + co] - mu_s[t]) * rs_s[t] * g2[co] + be2[co];
        }
        __syncthreads();

        // ----- FF1 (relu) -> big stride 516
        for (int f = tid; f < TT * 512; f += 256) {
            int t = f >> 9, j = f & 511;
            const float* wrow = W1l + j * 128;
            const float* hrow = sc1 + t * 132;
            float acc = b1l[j];
            for (int k = 0; k < 128; k += 4) {
                float4 h4 = *(const float4*)(hrow + k);
                float4 w4 = *(const float4*)(wrow + k);
                acc += h4.x * w4.x + h4.y * w4.y + h4.z * w4.z + h4.w * w4.w;
            }
            big[t * 516 + j] = fmaxf(acc, 0.f);
        }
        __syncthreads();

        // ----- FF2 + residual
        for (int f = tid; f < TT * 128; f += 256) {
            int t = f >> 7, co = f & 127;
            const float* wrow = W2l + co * 512;
            const float* hrow = big + t * 516;
            float acc = b2l[co];
            for (int j = 0; j < 512; j += 4) {
                float4 h4 = *(const float4*)(hrow + j);
                float4 w4 = *(const float4*)(wrow + j);
                acc += h4.x * w4.x + h4.y * w4.y + h4.z * w4.z + h4.w * w4.w;
            }
            a_s[t * 132 + co] += acc;
        }
        __syncthreads();
    }

    // act_emb (p=24) and mv_emb (p=25)
    if (tid < 128) {
        float s = 0.f;
#pragma unroll
        for (int t = 0; t < TT; t++) s += a_s[t * 132 + tid];
        out[(size_t)b * 26 * Cc + 24 * Cc + tid] = s * (1.f / 15.f);
    } else if (tid < 256) {
        int co = tid - 128;
        float v = ss[b] * Wsc[co] + bsc[co];
        out[(size_t)b * 26 * Cc + 25 * Cc + co] = fmaxf(v, 0.f);
    }
}

// ---------------------------------------------------------------------------
extern "C" void kernel_launch(void* const* d_in, const int* in_sizes, int n_in,
                              void* d_out, int out_size, void* d_ws, size_t ws_size,
                              hipStream_t stream)
{
    (void)in_sizes; (void)n_in; (void)out_size; (void)ws_size;
    const int*   xx   = (const int*)d_in[0];
    const float* ss   = (const float*)d_in[1];
    const float* Win  = (const float*)d_in[2];
    const float* b_in = (const float*)d_in[3];
    const float* Wl   = (const float*)d_in[4];
    const float* bl   = (const float*)d_in[5];
    const float* Wr   = (const float*)d_in[6];
    const float* lng  = (const float*)d_in[7];
    const float* lnb  = (const float*)d_in[8];
    const float* Wqkv = (const float*)d_in[9];
    const float* bqkv = (const float*)d_in[10];
    const float* Wo   = (const float*)d_in[11];
    const float* bo   = (const float*)d_in[12];
    const float* ln1g = (const float*)d_in[13];
    const float* ln1b = (const float*)d_in[14];
    const float* ln2g = (const float*)d_in[15];
    const float* ln2b = (const float*)d_in[16];
    const float* W1   = (const float*)d_in[17];
    const float* b1   = (const float*)d_in[18];
    const float* W2   = (const float*)d_in[19];
    const float* b2   = (const float*)d_in[20];
    const float* Wact = (const float*)d_in[21];
    const float* bact = (const float*)d_in[22];
    const float* Wsc  = (const float*)d_in[23];
    const float* bsc  = (const float*)d_in[24];
    float* out = (float*)d_out;

    char* ws = (char*)d_ws;
    bf16* xbuf = (bf16*)ws;
    size_t off = (size_t)Bsz * S3 * Cc * sizeof(bf16);          // 67,108,864
    float* sA   = (float*)(ws + off); off += (size_t)Bsz * Cc * 4;
    float* sB   = (float*)(ws + off); off += (size_t)Bsz * Cc * 4;
    float* invb = (float*)(ws + off); off += (size_t)Bsz * 4;
    float* mbuf = (float*)(ws + off); off += (size_t)Bsz * S3 * 4;

    k_init<<<Bsz, 256, 0, stream>>>(xx, ss, Win, b_in, xbuf, sA, invb, mbuf);

    hipMemsetAsync(sB, 0, (size_t)Bsz * Cc * 4, stream);
    k_gnn<<<Bsz * 8, 256, 0, stream>>>(xbuf, sA, invb,
                                       Wl,          bl,        Wr,
                                       lng, lnb, mbuf, sB, 1);
    hipMemsetAsync(sA, 0, (size_t)Bsz * Cc * 4, stream);
    k_gnn<<<Bsz * 8, 256, 0, stream>>>(xbuf, sB, invb,
                                       Wl + 16384,  bl + 128,  Wr + 16384,
                                       lng, lnb, mbuf, sA, 1);
    k_gnn<<<Bsz * 8, 256, 0, stream>>>(xbuf, sA, invb,
                                       Wl + 32768,  bl + 256,  Wr + 32768,
                                       lng, lnb, mbuf, sB, 0);

    k_pool<<<Bsz, 256, 0, stream>>>(xbuf, mbuf, out);

    k_tf<<<Bsz, 256, 0, stream>>>(xx, ss, Wqkv, bqkv, Wo, bo,
                                  ln1g, ln1b, ln2g, ln2b,
                                  W1, b1, W2, b2, Wact, bact, Wsc, bsc, out);
}

// Round 2
// 1131.221 us; speedup vs baseline: 2.4712x; 2.4712x over previous
//
#include <hip/hip_runtime.h>
#include <hip/hip_bf16.h>
#include <string.h>

typedef __hip_bfloat16 bf16;

#define Bsz 512
#define S3  512
#define Tsz 16
#define Cc  128
#define TT  15
#define EPSv 1e-5f

__device__ __forceinline__ float u2f(unsigned short u) {
    return __uint_as_float(((unsigned)u) << 16);
}
__device__ __forceinline__ float b2f(bf16 v) { return __bfloat162float(v); }
__device__ __forceinline__ bf16  f2b(float v) { return __float2bfloat16(v); }
__device__ __forceinline__ unsigned short f2bu(float v) {
    bf16 h = __float2bfloat16(v);
    unsigned short u; memcpy(&u, &h, 2); return u;
}
__device__ __forceinline__ float dot4(float4 a, float4 b) {
    return a.x*b.x + a.y*b.y + a.z*b.z + a.w*b.w;
}

// ---------------------------------------------------------------------------
// k_tpack: src (NR x NK) row-major fp32 -> dst float4-packed k-major:
//   ((float4*)dst)[k4*NR + r] = {src[r][4k4+0..3]}
// grid dim3(NK/32, NR/32), block 256. NR,NK multiples of 32.
// ---------------------------------------------------------------------------
__global__ __launch_bounds__(256) void k_tpack(const float* __restrict__ src,
                                               float* __restrict__ dst,
                                               int NR, int NK)
{
    __shared__ float tile[32][33];
    int k0 = blockIdx.x * 32, r0 = blockIdx.y * 32;
    int lr = threadIdx.x >> 5, lk = threadIdx.x & 31;
    for (int i = lr; i < 32; i += 8)
        tile[i][lk] = src[(size_t)(r0 + i) * NK + k0 + lk];
    __syncthreads();
    int c = threadIdx.x & 31, k4 = threadIdx.x >> 5;   // k4 in 0..7
    float4 v;
    v.x = tile[c][k4 * 4 + 0]; v.y = tile[c][k4 * 4 + 1];
    v.z = tile[c][k4 * 4 + 2]; v.w = tile[c][k4 * 4 + 3];
    ((float4*)dst)[(size_t)(k0 / 4 + k4) * NR + r0 + c] = v;
}

// ---------------------------------------------------------------------------
// k_init: features -> lin_in -> x0 (bf16), mask, n->inv, s0 (masked sum)
// one block of 512 threads per batch element; thread = (g=tid>>6, cp=tid&63)
// handles co {2cp, 2cp+1} for nodes {g, g+8, ...} -> 4B packed stores
// ---------------------------------------------------------------------------
__global__ __launch_bounds__(512) void k_init(
    const int* __restrict__ xx, const float* __restrict__ ss,
    const float* __restrict__ Win, const float* __restrict__ b_in,
    bf16* __restrict__ xbuf, float* __restrict__ sbuf,
    float* __restrict__ invbuf, float* __restrict__ mbuf)
{
    __shared__ float sred[8 * 128];
    __shared__ float scnt[8];
    int b = blockIdx.x, tid = threadIdx.x;
    int g = tid >> 6, cp = tid & 63;
    int co0 = 2 * cp, co1 = 2 * cp + 1;
    const int* x0 = xx + (size_t)b * Tsz * S3;
    float f4c = ss[b] * (1.0f / 8.0f);
    float a0 = Win[co0*5+0], a1 = Win[co0*5+1], a2 = Win[co0*5+2], a3 = Win[co0*5+3], a4 = Win[co0*5+4];
    float c0 = Win[co1*5+0], c1 = Win[co1*5+1], c2 = Win[co1*5+2], c3 = Win[co1*5+3], c4 = Win[co1*5+4];
    float ba = b_in[co0], bc = b_in[co1];
    unsigned* xo = (unsigned*)xbuf;

    float sp0 = 0.f, sp1 = 0.f; int cnt = 0;
    for (int node = g; node < S3; node += 8) {
        int f0 = x0[node];
        float m = (f0 != 0) ? 1.f : 0.f;
        float ci = (float)(node >> 6) * (1.f / 7.f);
        float cj = (float)((node >> 3) & 7) * (1.f / 7.f);
        float ck = (float)(node & 7) * (1.f / 7.f);
        float ft = (float)f0 * 0.5f;
        float v0 = ba + ci * a0 + cj * a1 + ck * a2 + ft * a3 + f4c * a4;
        float v1 = bc + ci * c0 + cj * c1 + ck * c2 + ft * c3 + f4c * c4;
        xo[(size_t)(b * S3 + node) * 64 + cp] = (unsigned)f2bu(v0) | ((unsigned)f2bu(v1) << 16);
        sp0 += v0 * m; sp1 += v1 * m;
        cnt += (f0 != 0);
        if (cp == 0) mbuf[b * S3 + node] = m;
    }
    sred[g * 128 + co0] = sp0;
    sred[g * 128 + co1] = sp1;
    if (cp == 0) scnt[g] = (float)cnt;
    __syncthreads();
    if (tid < 128) {
        float s = 0.f;
#pragma unroll
        for (int gg = 0; gg < 8; gg++) s += sred[gg * 128 + tid];
        sbuf[b * Cc + tid] = s;
    }
    if (tid == 0) {
        float n = 0.f;
#pragma unroll
        for (int gg = 0; gg < 8; gg++) n += scnt[gg];
        invbuf[b] = (n > 1.f) ? 1.f / (n - 1.f) : 0.f;
    }
}

// ---------------------------------------------------------------------------
// k_gnn: one SAGE layer, in-place x update. Weights via packed-transposed
// layout: WlP/WrP are float4 arrays [k4*384 + (l*128 + co)].
// ---------------------------------------------------------------------------
__global__ __launch_bounds__(256) void k_gnn(
    bf16* __restrict__ xbuf,
    const float* __restrict__ sIn, const float* __restrict__ invbuf,
    const float4* __restrict__ WlP, const float* __restrict__ blv,
    const float4* __restrict__ WrP, int lbase,
    const float* __restrict__ lng, const float* __restrict__ lnb,
    const float* __restrict__ mbuf,
    float* __restrict__ sout, int acc_s)
{
    __shared__ float smem[64 * 129];   // x phase: stride 128; h phase: stride 129
    __shared__ float sinv[128];
    __shared__ float stats[128];
    __shared__ float sred[512];

    int tid = threadIdx.x;
    int b = blockIdx.x >> 3;
    int node0 = (blockIdx.x & 7) * 64;
    float inv = invbuf[b];

    const ushort4* xg4 = (const ushort4*)(xbuf + (size_t)(b * S3 + node0) * Cc);
    for (int f = tid; f < 2048; f += 256) {
        ushort4 u = xg4[f];
        float4 v;
        v.x = u2f(u.x); v.y = u2f(u.y); v.z = u2f(u.z); v.w = u2f(u.w);
        ((float4*)smem)[f] = v;
    }
    if (tid < 128) sinv[tid] = sIn[b * Cc + tid] * inv;
    __syncthreads();

    int co0 = tid & 63;
    int co1 = co0 + 64;
    int g = tid >> 6;
    int r0 = lbase + co0, r1 = lbase + co1;

    float acc0[16], acc1[16];
#pragma unroll
    for (int i = 0; i < 16; i++) { acc0[i] = 0.f; acc1[i] = 0.f; }
    float base0 = blv[co0], base1 = blv[co1];

    for (int k4 = 0; k4 < 32; k4++) {
        float4 wl0 = WlP[k4 * 384 + r0];
        float4 wl1 = WlP[k4 * 384 + r1];
        float4 wr0 = WrP[k4 * 384 + r0];
        float4 wr1 = WrP[k4 * 384 + r1];
        float4 sv = *(const float4*)(sinv + k4 * 4);
        base0 += dot4(sv, wl0);
        base1 += dot4(sv, wl1);
        float4 d0, d1;
        d0.x = wr0.x - inv * wl0.x; d0.y = wr0.y - inv * wl0.y;
        d0.z = wr0.z - inv * wl0.z; d0.w = wr0.w - inv * wl0.w;
        d1.x = wr1.x - inv * wl1.x; d1.y = wr1.y - inv * wl1.y;
        d1.z = wr1.z - inv * wl1.z; d1.w = wr1.w - inv * wl1.w;
        const float* xs = smem + (g * 16) * Cc + k4 * 4;
#pragma unroll
        for (int i = 0; i < 16; i++) {
            float4 xv = *(const float4*)(xs + i * Cc);
            acc0[i] += dot4(xv, d0);
            acc1[i] += dot4(xv, d1);
        }
    }
    __syncthreads();

#pragma unroll
    for (int i = 0; i < 16; i++) {
        int node = g * 16 + i;
        smem[node * 129 + co0] = fmaxf(acc0[i] + base0, 0.f);
        smem[node * 129 + co1] = fmaxf(acc1[i] + base1, 0.f);
    }
    __syncthreads();

    if (tid < 64) {
        const float* row = smem + tid * 129;
        float s = 0.f, s2 = 0.f;
        for (int j = 0; j < 128; j++) { float v = row[j]; s += v; s2 += v * v; }
        float mu = s * (1.f / 128.f);
        float var = s2 * (1.f / 128.f) - mu * mu;
        stats[tid] = mu;
        stats[64 + tid] = rsqrtf(var + EPSv);
    }
    __syncthreads();

    float gg0 = lng[co0], gg1 = lng[co1], be0 = lnb[co0], be1 = lnb[co1];
    float sp0 = 0.f, sp1 = 0.f;
    bf16* xo = xbuf + (size_t)(b * S3 + node0) * Cc;
#pragma unroll
    for (int i = 0; i < 16; i++) {
        int node = g * 16 + i;
        float mu = stats[node], rs = stats[64 + node];
        float y0 = (smem[node * 129 + co0] - mu) * rs * gg0 + be0;
        float y1 = (smem[node * 129 + co1] - mu) * rs * gg1 + be1;
        xo[node * Cc + co0] = f2b(y0);
        xo[node * Cc + co1] = f2b(y1);
        float m = mbuf[b * S3 + node0 + node];
        sp0 += y0 * m;
        sp1 += y1 * m;
    }
    if (acc_s) {
        sred[g * 128 + co0] = sp0;
        sred[g * 128 + co1] = sp1;
        __syncthreads();
        if (tid < 128) {
            float t = sred[tid] + sred[128 + tid] + sred[256 + tid] + sred[384 + tid];
            atomicAdd(&sout[b * Cc + tid], t);
        }
    }
}

// ---------------------------------------------------------------------------
// k_pool: gnn_emb = slice means of (x * m) -> out[b][0..23][c]
// ---------------------------------------------------------------------------
__global__ __launch_bounds__(256) void k_pool(
    const bf16* __restrict__ xbuf, const float* __restrict__ mbuf,
    float* __restrict__ out)
{
    int b = blockIdx.x, tid = threadIdx.x;
    for (int f = tid; f < 24 * 128; f += 256) {
        int p = f >> 7, c = f & 127;
        int axis = p >> 3, idx = p & 7;
        float sum = 0.f;
        for (int t = 0; t < 64; t++) {
            int node;
            if (axis == 0)      node = idx * 64 + t;
            else if (axis == 1) node = (t >> 3) * 64 + idx * 8 + (t & 7);
            else                node = t * 8 + idx;
            sum += b2f(xbuf[(size_t)(b * S3 + node) * Cc + c]) * mbuf[b * S3 + node];
        }
        out[(size_t)b * 26 * Cc + p * Cc + c] = sum * (1.f / 64.f);
    }
}

// ---------------------------------------------------------------------------
// k_tf2: full transformer per batch element. 384 threads, register-tiled
// GEMMs with packed-transposed weights (coalesced b128 weight loads) and
// LDS-broadcast activations.
// ---------------------------------------------------------------------------
__global__ __launch_bounds__(384, 3) void k_tf2(
    const int* __restrict__ xx, const float* __restrict__ ss,
    const float4* __restrict__ WactP, const float* __restrict__ bact,
    const float4* __restrict__ WqkvP, const float* __restrict__ bqkv,
    const float4* __restrict__ WoP, const float* __restrict__ bo,
    const float* __restrict__ ln1g, const float* __restrict__ ln1b,
    const float* __restrict__ ln2g, const float* __restrict__ ln2b,
    const float4* __restrict__ W1P, const float* __restrict__ b1v,
    const float4* __restrict__ W2P, const float* __restrict__ b2v,
    const float* __restrict__ Wsc, const float* __restrict__ bsc,
    float* __restrict__ out)
{
    __shared__ float As[TT * 132];
    __shared__ float Hs[TT * 132];
    __shared__ float Qs[TT * 388];
    __shared__ float Fs[TT * 516];
    __shared__ float Att[60 * 16];
    __shared__ float mu_s[TT], rs_s[TT];

    int b = blockIdx.x, tid = threadIdx.x;

    // ---- stage action frames as float
    const int* xa = xx + (size_t)b * Tsz * S3 + S3;
    for (int f = tid; f < TT * 512; f += 384) {
        int t = f >> 9, s = f & 511;
        Fs[t * 516 + s] = (float)xa[t * 512 + s];
    }
    __syncthreads();

    // ---- embed: As[t][co] = Fs[t] . Wact[co] + bact[co]   (K=512)
    {
        int cp = tid & 63, g = tid >> 6;          // g 0..5
        int nt = (g < 3) ? 3 : 2;
        float acc[3][2] = {};
        for (int k4 = 0; k4 < 128; k4++) {
            float4 wa = WactP[k4 * 128 + cp];
            float4 wb = WactP[k4 * 128 + cp + 64];
#pragma unroll
            for (int it = 0; it < 3; it++) if (it < nt) {
                int t = g + it * 6;
                float4 xv = *(const float4*)(Fs + t * 516 + k4 * 4);
                acc[it][0] += dot4(xv, wa);
                acc[it][1] += dot4(xv, wb);
            }
        }
        float b0 = bact[cp], b1b = bact[cp + 64];
        for (int it = 0; it < nt; it++) {
            int t = g + it * 6;
            As[t * 132 + cp]      = acc[it][0] + b0;
            As[t * 132 + cp + 64] = acc[it][1] + b1b;
        }
    }
    __syncthreads();

    for (int l = 0; l < 2; l++) {
        const float* bq  = bqkv + l * 384;
        const float* bol = bo + l * 128;
        const float* g1  = ln1g + l * 128; const float* be1 = ln1b + l * 128;
        const float* g2  = ln2g + l * 128; const float* be2 = ln2b + l * 128;
        const float* b1l = b1v + l * 512;  const float* b2l = b2v + l * 128;

        // ---- LN1: stats via wave shuffle
        {
            int wv = tid >> 6, ln = tid & 63;
            for (int r = wv; r < TT; r += 6) {
                float2 v = *(const float2*)(As + r * 132 + ln * 2);
                float s = v.x + v.y, q = v.x * v.x + v.y * v.y;
                for (int off = 32; off; off >>= 1) {
                    s += __shfl_xor(s, off, 64);
                    q += __shfl_xor(q, off, 64);
                }
                if (ln == 0) {
                    float mu = s * (1.f / 128.f);
                    mu_s[r] = mu;
                    rs_s[r] = rsqrtf(q * (1.f / 128.f) - mu * mu + EPSv);
                }
            }
        }
        __syncthreads();
        for (int f = tid; f < TT * 128; f += 384) {
            int t = f >> 7, co = f & 127;
            Hs[t * 132 + co] = (As[t * 132 + co] - mu_s[t]) * rs_s[t] * g1[co] + be1[co];
        }
        __syncthreads();

        // ---- qkv: Qs[t][co] = Hs[t] . Wqkv[co] + bq[co]   (K=128, N=384)
        {
            int cp = tid % 192, g = tid / 192;
            int t0 = g * 8, nt = g ? 7 : 8;
            int ra = l * 384 + cp, rb = ra + 192;
            float acc[8][2] = {};
            for (int k4 = 0; k4 < 32; k4++) {
                float4 wa = WqkvP[k4 * 768 + ra];
                float4 wb = WqkvP[k4 * 768 + rb];
#pragma unroll
                for (int it = 0; it < 8; it++) if (it < nt) {
                    float4 xv = *(const float4*)(Hs + (t0 + it) * 132 + k4 * 4);
                    acc[it][0] += dot4(xv, wa);
                    acc[it][1] += dot4(xv, wb);
                }
            }
            float b0 = bq[cp], b1b = bq[cp + 192];
            for (int it = 0; it < nt; it++) {
                Qs[(t0 + it) * 388 + cp]       = acc[it][0] + b0;
                Qs[(t0 + it) * 388 + cp + 192] = acc[it][1] + b1b;
            }
        }
        __syncthreads();

        // ---- attention scores + softmax (60 threads)
        if (tid < 60) {
            int h = tid / 15, tq = tid % 15;
            const float* qp = Qs + tq * 388 + h * 32;
            float sc[TT];
            float mx = -1e30f;
#pragma unroll
            for (int tk = 0; tk < TT; tk++) {
                const float* kp = Qs + tk * 388 + 128 + h * 32;
                float d = 0.f;
#pragma unroll
                for (int u = 0; u < 32; u += 4)
                    d += dot4(*(const float4*)(qp + u), *(const float4*)(kp + u));
                d *= 0.17677669529663689f;
                sc[tk] = d; mx = fmaxf(mx, d);
            }
            float sum = 0.f;
#pragma unroll
            for (int tk = 0; tk < TT; tk++) { float e = __expf(sc[tk] - mx); sc[tk] = e; sum += e; }
            float r = 1.f / sum;
#pragma unroll
            for (int tk = 0; tk < TT; tk++) Att[tid * 16 + tk] = sc[tk] * r;
        }
        __syncthreads();

        // ---- o = att @ v  -> Hs
        for (int f = tid; f < TT * 128; f += 384) {
            int t = f >> 7, co = f & 127;
            int h = co >> 5;
            const float* ap = Att + (h * 15 + t) * 16;
            const float* vp = Qs + 256 + co;
            float acc = 0.f;
#pragma unroll
            for (int tk = 0; tk < TT; tk++) acc += ap[tk] * vp[tk * 388];
            Hs[t * 132 + co] = acc;
        }
        __syncthreads();

        // ---- proj + residual into As   (K=128, N=128)
        {
            int cp = tid & 63, g = tid >> 6;
            int nt = (g < 3) ? 3 : 2;
            int ra = l * 128 + cp, rb = ra + 64;
            float acc[3][2] = {};
            for (int k4 = 0; k4 < 32; k4++) {
                float4 wa = WoP[k4 * 256 + ra];
                float4 wb = WoP[k4 * 256 + rb];
#pragma unroll
                for (int it = 0; it < 3; it++) if (it < nt) {
                    int t = g + it * 6;
                    float4 xv = *(const float4*)(Hs + t * 132 + k4 * 4);
                    acc[it][0] += dot4(xv, wa);
                    acc[it][1] += dot4(xv, wb);
                }
            }
            float b0 = bol[cp], b1b = bol[cp + 64];
            for (int it = 0; it < nt; it++) {
                int t = g + it * 6;
                As[t * 132 + cp]      += acc[it][0] + b0;
                As[t * 132 + cp + 64] += acc[it][1] + b1b;
            }
        }
        __syncthreads();

        // ---- LN2
        {
            int wv = tid >> 6, ln = tid & 63;
            for (int r = wv; r < TT; r += 6) {
                float2 v = *(const float2*)(As + r * 132 + ln * 2);
                float s = v.x + v.y, q = v.x * v.x + v.y * v.y;
                for (int off = 32; off; off >>= 1) {
                    s += __shfl_xor(s, off, 64);
                    q += __shfl_xor(q, off, 64);
                }
                if (ln == 0) {
                    float mu = s * (1.f / 128.f);
                    mu_s[r] = mu;
                    rs_s[r] = rsqrtf(q * (1.f / 128.f) - mu * mu + EPSv);
                }
            }
        }
        __syncthreads();
        for (int f = tid; f < TT * 128; f += 384) {
            int t = f >> 7, co = f & 127;
            Hs[t * 132 + co] = (As[t * 132 + co] - mu_s[t]) * rs_s[t] * g2[co] + be2[co];
        }
        __syncthreads();

        // ---- FF1 (relu) -> Fs   (K=128, N=512)
        {
            int cp = tid & 127, g = tid >> 7;     // g 0..2
            int r0 = l * 512 + cp;
            float acc[5][4] = {};
            for (int k4 = 0; k4 < 32; k4++) {
                float4 w0 = W1P[k4 * 1024 + r0];
                float4 w1 = W1P[k4 * 1024 + r0 + 128];
                float4 w2 = W1P[k4 * 1024 + r0 + 256];
                float4 w3 = W1P[k4 * 1024 + r0 + 384];
#pragma unroll
                for (int it = 0; it < 5; it++) {
                    int t = g + it * 3;
                    float4 xv = *(const float4*)(Hs + t * 132 + k4 * 4);
                    acc[it][0] += dot4(xv, w0);
                    acc[it][1] += dot4(xv, w1);
                    acc[it][2] += dot4(xv, w2);
                    acc[it][3] += dot4(xv, w3);
                }
            }
            float bb0 = b1l[cp], bb1 = b1l[cp + 128], bb2 = b1l[cp + 256], bb3 = b1l[cp + 384];
            for (int it = 0; it < 5; it++) {
                int t = g + it * 3;
                Fs[t * 516 + cp]       = fmaxf(acc[it][0] + bb0, 0.f);
                Fs[t * 516 + cp + 128] = fmaxf(acc[it][1] + bb1, 0.f);
                Fs[t * 516 + cp + 256] = fmaxf(acc[it][2] + bb2, 0.f);
                Fs[t * 516 + cp + 384] = fmaxf(acc[it][3] + bb3, 0.f);
            }
        }
        __syncthreads();

        // ---- FF2 + residual into As   (K=512, N=128)
        {
            int cp = tid & 63, g = tid >> 6;
            int nt = (g < 3) ? 3 : 2;
            int ra = l * 128 + cp, rb = ra + 64;
            float acc[3][2] = {};
            for (int k4 = 0; k4 < 128; k4++) {
                float4 wa = W2P[k4 * 256 + ra];
                float4 wb = W2P[k4 * 256 + rb];
#pragma unroll
                for (int it = 0; it < 3; it++) if (it < nt) {
                    int t = g + it * 6;
                    float4 xv = *(const float4*)(Fs + t * 516 + k4 * 4);
                    acc[it][0] += dot4(xv, wa);
                    acc[it][1] += dot4(xv, wb);
                }
            }
            float b0 = b2l[cp], b1b = b2l[cp + 64];
            for (int it = 0; it < nt; it++) {
                int t = g + it * 6;
                As[t * 132 + cp]      += acc[it][0] + b0;
                As[t * 132 + cp + 64] += acc[it][1] + b1b;
            }
        }
        __syncthreads();
    }

    // ---- tail: act_emb + mv_emb
    if (tid < 128) {
        float s = 0.f;
#pragma unroll
        for (int t = 0; t < TT; t++) s += As[t * 132 + tid];
        out[(size_t)b * 26 * Cc + 24 * Cc + tid] = s * (1.f / 15.f);
    } else if (tid < 256) {
        int co = tid - 128;
        float v = ss[b] * Wsc[co] + bsc[co];
        out[(size_t)b * 26 * Cc + 25 * Cc + co] = fmaxf(v, 0.f);
    }
}

// ---------------------------------------------------------------------------
extern "C" void kernel_launch(void* const* d_in, const int* in_sizes, int n_in,
                              void* d_out, int out_size, void* d_ws, size_t ws_size,
                              hipStream_t stream)
{
    (void)in_sizes; (void)n_in; (void)out_size; (void)ws_size;
    const int*   xx   = (const int*)d_in[0];
    const float* ss   = (const float*)d_in[1];
    const float* Win  = (const float*)d_in[2];
    const float* b_in = (const float*)d_in[3];
    const float* Wl   = (const float*)d_in[4];
    const float* bl   = (const float*)d_in[5];
    const float* Wr   = (const float*)d_in[6];
    const float* lng  = (const float*)d_in[7];
    const float* lnb  = (const float*)d_in[8];
    const float* Wqkv = (const float*)d_in[9];
    const float* bqkv = (const float*)d_in[10];
    const float* Wo   = (const float*)d_in[11];
    const float* bo   = (const float*)d_in[12];
    const float* ln1g = (const float*)d_in[13];
    const float* ln1b = (const float*)d_in[14];
    const float* ln2g = (const float*)d_in[15];
    const float* ln2b = (const float*)d_in[16];
    const float* W1   = (const float*)d_in[17];
    const float* b1   = (const float*)d_in[18];
    const float* W2   = (const float*)d_in[19];
    const float* b2   = (const float*)d_in[20];
    const float* Wact = (const float*)d_in[21];
    const float* bact = (const float*)d_in[22];
    const float* Wsc  = (const float*)d_in[23];
    const float* bsc  = (const float*)d_in[24];
    float* out = (float*)d_out;

    char* ws = (char*)d_ws;
    size_t off = 0;
    bf16*  xbuf = (bf16*)(ws + off); off += (size_t)Bsz * S3 * Cc * 2;
    float* sA   = (float*)(ws + off); off += (size_t)Bsz * Cc * 4;
    float* sB   = (float*)(ws + off); off += (size_t)Bsz * Cc * 4;
    float* invb = (float*)(ws + off); off += (size_t)Bsz * 4;
    float* mbuf = (float*)(ws + off); off += (size_t)Bsz * S3 * 4;
    float* WactT = (float*)(ws + off); off += 512 * 128 * 4;
    float* WqkvT = (float*)(ws + off); off += 768 * 128 * 4;
    float* WoT   = (float*)(ws + off); off += 256 * 128 * 4;
    float* W1T   = (float*)(ws + off); off += 1024 * 128 * 4;
    float* W2T   = (float*)(ws + off); off += 256 * 512 * 4;
    float* WlT   = (float*)(ws + off); off += 384 * 128 * 4;
    float* WrT   = (float*)(ws + off); off += 384 * 128 * 4;

    // weight pre-transposes (k-major float4-packed)
    k_tpack<<<dim3(16, 4),  256, 0, stream>>>(Wact, WactT, 128, 512);
    k_tpack<<<dim3(4, 24),  256, 0, stream>>>(Wqkv, WqkvT, 768, 128);
    k_tpack<<<dim3(4, 8),   256, 0, stream>>>(Wo,   WoT,   256, 128);
    k_tpack<<<dim3(4, 32),  256, 0, stream>>>(W1,   W1T,  1024, 128);
    k_tpack<<<dim3(16, 8),  256, 0, stream>>>(W2,   W2T,   256, 512);
    k_tpack<<<dim3(4, 12),  256, 0, stream>>>(Wl,   WlT,   384, 128);
    k_tpack<<<dim3(4, 12),  256, 0, stream>>>(Wr,   WrT,   384, 128);

    k_init<<<Bsz, 512, 0, stream>>>(xx, ss, Win, b_in, xbuf, sA, invb, mbuf);

    hipMemsetAsync(sB, 0, (size_t)Bsz * Cc * 4, stream);
    k_gnn<<<Bsz * 8, 256, 0, stream>>>(xbuf, sA, invb,
                                       (const float4*)WlT, bl,       (const float4*)WrT, 0,
                                       lng, lnb, mbuf, sB, 1);
    hipMemsetAsync(sA, 0, (size_t)Bsz * Cc * 4, stream);
    k_gnn<<<Bsz * 8, 256, 0, stream>>>(xbuf, sB, invb,
                                       (const float4*)WlT, bl + 128, (const float4*)WrT, 128,
                                       lng, lnb, mbuf, sA, 1);
    k_gnn<<<Bsz * 8, 256, 0, stream>>>(xbuf, sA, invb,
                                       (const float4*)WlT, bl + 256, (const float4*)WrT, 256,
                                       lng, lnb, mbuf, sB, 0);

    k_pool<<<Bsz, 256, 0, stream>>>(xbuf, mbuf, out);

    k_tf2<<<Bsz, 384, 0, stream>>>(xx, ss,
                                   (const float4*)WactT, bact,
                                   (const float4*)WqkvT, bqkv,
                                   (const float4*)WoT,   bo,
                                   ln1g, ln1b, ln2g, ln2b,
                                   (const float4*)W1T,   b1,
                                   (const float4*)W2T,   b2,
                                   Wsc, bsc, out);
}

// Round 3
// 888.586 us; speedup vs baseline: 3.1460x; 1.2731x over previous
//
#include <hip/hip_runtime.h>
#include <hip/hip_bf16.h>
#include <string.h>

typedef __hip_bfloat16 bf16;
typedef __attribute__((ext_vector_type(8))) short short8;
typedef __attribute__((ext_vector_type(4))) float f32x4;

#define Bsz 512
#define S3  512
#define Tsz 16
#define Cc  128
#define TT  15
#define EPSv 1e-5f

__device__ __forceinline__ float u2f(unsigned short u) {
    return __uint_as_float(((unsigned)u) << 16);
}
__device__ __forceinline__ float b2f(bf16 v) { return __bfloat162float(v); }
__device__ __forceinline__ bf16  f2b(float v) { return __float2bfloat16(v); }
__device__ __forceinline__ unsigned short f2bu(float v) {
    bf16 h = __float2bfloat16(v);
    unsigned short u; memcpy(&u, &h, 2); return u;
}
__device__ __forceinline__ float dot4(float4 a, float4 b) {
    return a.x*b.x + a.y*b.y + a.z*b.z + a.w*b.w;
}

// ---------------------------------------------------------------------------
// k_tpack: src (NR x NK) row-major fp32 -> float4-packed k-major:
//   ((float4*)dst)[k4*NR + r] = {src[r][4k4+0..3]}
// ---------------------------------------------------------------------------
__global__ __launch_bounds__(256) void k_tpack(const float* __restrict__ src,
                                               float* __restrict__ dst,
                                               int NR, int NK)
{
    __shared__ float tile[32][33];
    int k0 = blockIdx.x * 32, r0 = blockIdx.y * 32;
    int lr = threadIdx.x >> 5, lk = threadIdx.x & 31;
    for (int i = lr; i < 32; i += 8)
        tile[i][lk] = src[(size_t)(r0 + i) * NK + k0 + lk];
    __syncthreads();
    int c = threadIdx.x & 31, k4 = threadIdx.x >> 5;
    float4 v;
    v.x = tile[c][k4 * 4 + 0]; v.y = tile[c][k4 * 4 + 1];
    v.z = tile[c][k4 * 4 + 2]; v.w = tile[c][k4 * 4 + 3];
    ((float4*)dst)[(size_t)(k0 / 4 + k4) * NR + r0 + c] = v;
}

// ---------------------------------------------------------------------------
// k_dw: per-batch combined GNN weight d = Wr - inv*Wl  -> bf16 (128x128,
// row n = c_out, k-contiguous). One block per batch; layer picked by pointers.
// ---------------------------------------------------------------------------
__global__ __launch_bounds__(256) void k_dw(
    const float* __restrict__ Wl, const float* __restrict__ Wr,
    const float* __restrict__ invbuf, ushort* __restrict__ dbuf)
{
    int b = blockIdx.x;
    float inv = invbuf[b];
    ushort4* dst = (ushort4*)(dbuf + (size_t)b * 16384);
    const float4* wl4 = (const float4*)Wl;
    const float4* wr4 = (const float4*)Wr;
    for (int f = threadIdx.x; f < 4096; f += 256) {
        float4 a = wl4[f];
        float4 r = wr4[f];
        ushort4 o;
        o.x = f2bu(r.x - inv * a.x); o.y = f2bu(r.y - inv * a.y);
        o.z = f2bu(r.z - inv * a.z); o.w = f2bu(r.w - inv * a.w);
        dst[f] = o;
    }
}

// ---------------------------------------------------------------------------
// k_init: features -> lin_in -> x0 (bf16), mask, n->inv, s0
// ---------------------------------------------------------------------------
__global__ __launch_bounds__(512) void k_init(
    const int* __restrict__ xx, const float* __restrict__ ss,
    const float* __restrict__ Win, const float* __restrict__ b_in,
    bf16* __restrict__ xbuf, float* __restrict__ sbuf,
    float* __restrict__ invbuf, float* __restrict__ mbuf)
{
    __shared__ float sred[8 * 128];
    __shared__ float scnt[8];
    int b = blockIdx.x, tid = threadIdx.x;
    int g = tid >> 6, cp = tid & 63;
    int co0 = 2 * cp, co1 = 2 * cp + 1;
    const int* x0 = xx + (size_t)b * Tsz * S3;
    float f4c = ss[b] * (1.0f / 8.0f);
    float a0 = Win[co0*5+0], a1 = Win[co0*5+1], a2 = Win[co0*5+2], a3 = Win[co0*5+3], a4 = Win[co0*5+4];
    float c0 = Win[co1*5+0], c1 = Win[co1*5+1], c2 = Win[co1*5+2], c3 = Win[co1*5+3], c4 = Win[co1*5+4];
    float ba = b_in[co0], bc = b_in[co1];
    unsigned* xo = (unsigned*)xbuf;

    float sp0 = 0.f, sp1 = 0.f; int cnt = 0;
    for (int node = g; node < S3; node += 8) {
        int f0 = x0[node];
        float m = (f0 != 0) ? 1.f : 0.f;
        float ci = (float)(node >> 6) * (1.f / 7.f);
        float cj = (float)((node >> 3) & 7) * (1.f / 7.f);
        float ck = (float)(node & 7) * (1.f / 7.f);
        float ft = (float)f0 * 0.5f;
        float v0 = ba + ci * a0 + cj * a1 + ck * a2 + ft * a3 + f4c * a4;
        float v1 = bc + ci * c0 + cj * c1 + ck * c2 + ft * c3 + f4c * c4;
        xo[(size_t)(b * S3 + node) * 64 + cp] = (unsigned)f2bu(v0) | ((unsigned)f2bu(v1) << 16);
        sp0 += v0 * m; sp1 += v1 * m;
        cnt += (f0 != 0);
        if (cp == 0) mbuf[b * S3 + node] = m;
    }
    sred[g * 128 + co0] = sp0;
    sred[g * 128 + co1] = sp1;
    if (cp == 0) scnt[g] = (float)cnt;
    __syncthreads();
    if (tid < 128) {
        float s = 0.f;
#pragma unroll
        for (int gg = 0; gg < 8; gg++) s += sred[gg * 128 + tid];
        sbuf[b * Cc + tid] = s;
    }
    if (tid == 0) {
        float n = 0.f;
#pragma unroll
        for (int gg = 0; gg < 8; gg++) n += scnt[gg];
        invbuf[b] = (n > 1.f) ? 1.f / (n - 1.f) : 0.f;
    }
}

// ---------------------------------------------------------------------------
// k_gnn (MFMA): one SAGE layer. blockIdx: batch = bi & 511, tile = bi >> 9
// (same-batch tiles share an XCD under round-robin dispatch -> d stays in L2).
// LDS: A (64x136 bf16) + B (128x136 bf16) = 52 KB, h (64x129 f32) overlaid.
// ---------------------------------------------------------------------------
__global__ __launch_bounds__(256) void k_gnn(
    bf16* __restrict__ xbuf,
    const float* __restrict__ sIn, const float* __restrict__ invbuf,
    const ushort* __restrict__ dbuf,
    const float4* __restrict__ WlP, int lbase, const float* __restrict__ blv,
    const float* __restrict__ lng, const float* __restrict__ lnb,
    const float* __restrict__ mbuf,
    float* __restrict__ sout, int acc_s)
{
    __shared__ char raw[(64 * 136 + 128 * 136) * 2];   // 52224 B
    __shared__ float sinv[128];
    __shared__ float sbase[128];
    __shared__ float stats[128];
    __shared__ float sred[512];

    ushort* Abuf = (ushort*)raw;
    ushort* Bbuf = Abuf + 64 * 136;

    int tid = threadIdx.x;
    int b = blockIdx.x & 511;
    int node0 = (blockIdx.x >> 9) * 64;
    float inv = invbuf[b];

    // stage x tile (64 nodes x 128 ch bf16) -> A, row stride 136
    const ushort4* xg4 = (const ushort4*)(xbuf + (size_t)(b * S3 + node0) * Cc);
    for (int f = tid; f < 2048; f += 256) {
        int node = f >> 5, pos = f & 31;
        ((ushort4*)(Abuf + node * 136))[pos] = xg4[f];
    }
    // stage d (128x128 bf16) -> B, row stride 136
    const ushort4* dg4 = (const ushort4*)(dbuf + (size_t)b * 16384);
    for (int f = tid; f < 4096; f += 256) {
        int row = f >> 5, pos = f & 31;
        ((ushort4*)(Bbuf + row * 136))[pos] = dg4[f];
    }
    if (tid < 128) sinv[tid] = sIn[b * Cc + tid] * inv;
    __syncthreads();

    // base[c] = bl[c] + sum_k sinv[k] * Wl[c][k]   (coalesced packed Wl)
    if (tid < 128) {
        float acc = blv[tid];
        for (int k4 = 0; k4 < 32; k4++) {
            float4 w = WlP[k4 * 384 + lbase + tid];
            float4 s4 = *(const float4*)(sinv + k4 * 4);
            acc += dot4(s4, w);
        }
        sbase[tid] = acc;
    }

    // MFMA: wave wv handles m-rows [wv*16, wv*16+16), all 8 n-tiles
    int wv = tid >> 6, lane = tid & 63;
    int ml = lane & 15, quad = lane >> 4;
    const ushort* arow  = Abuf + (wv * 16 + ml) * 136 + quad * 8;
    const ushort* bbase = Bbuf + ml * 136 + quad * 8;

    f32x4 acc[8];
#pragma unroll
    for (int t = 0; t < 8; t++) acc[t] = (f32x4){0.f, 0.f, 0.f, 0.f};

#pragma unroll
    for (int ks = 0; ks < 4; ks++) {
        short8 a = *(const short8*)(arow + ks * 32);
        const ushort* bk = bbase + ks * 32;
#pragma unroll
        for (int t = 0; t < 8; t++) {
            short8 bf = *(const short8*)(bk + t * (16 * 136));
            acc[t] = __builtin_amdgcn_mfma_f32_16x16x32_bf16(a, bf, acc[t], 0, 0, 0);
        }
    }
    __syncthreads();   // A/B dead; reuse raw as h (stride 129)

    float* hbuf = (float*)raw;
#pragma unroll
    for (int t = 0; t < 8; t++) {
#pragma unroll
        for (int r = 0; r < 4; r++) {
            int row = wv * 16 + quad * 4 + r;
            int col = t * 16 + ml;
            hbuf[row * 129 + col] = fmaxf(acc[t][r] + sbase[col], 0.f);
        }
    }
    __syncthreads();

    if (tid < 64) {
        const float* row = hbuf + tid * 129;
        float s = 0.f, s2 = 0.f;
        for (int j = 0; j < 128; j++) { float v = row[j]; s += v; s2 += v * v; }
        float mu = s * (1.f / 128.f);
        float var = s2 * (1.f / 128.f) - mu * mu;
        stats[tid] = mu;
        stats[64 + tid] = rsqrtf(var + EPSv);
    }
    __syncthreads();

    int co0 = tid & 63, co1 = co0 + 64, g = tid >> 6;
    float gg0 = lng[co0], gg1 = lng[co1], be0 = lnb[co0], be1 = lnb[co1];
    float sp0 = 0.f, sp1 = 0.f;
    bf16* xo = xbuf + (size_t)(b * S3 + node0) * Cc;
#pragma unroll
    for (int i = 0; i < 16; i++) {
        int node = g * 16 + i;
        float mu = stats[node], rs = stats[64 + node];
        float y0 = (hbuf[node * 129 + co0] - mu) * rs * gg0 + be0;
        float y1 = (hbuf[node * 129 + co1] - mu) * rs * gg1 + be1;
        xo[node * Cc + co0] = f2b(y0);
        xo[node * Cc + co1] = f2b(y1);
        float m = mbuf[b * S3 + node0 + node];
        sp0 += y0 * m;
        sp1 += y1 * m;
    }
    if (acc_s) {
        sred[g * 128 + co0] = sp0;
        sred[g * 128 + co1] = sp1;
        __syncthreads();
        if (tid < 128) {
            float t = sred[tid] + sred[128 + tid] + sred[256 + tid] + sred[384 + tid];
            atomicAdd(&sout[b * Cc + tid], t);
        }
    }
}

// ---------------------------------------------------------------------------
// k_pool: gnn_emb = slice means of (x * m) -> out[b][0..23][c]
// ---------------------------------------------------------------------------
__global__ __launch_bounds__(256) void k_pool(
    const bf16* __restrict__ xbuf, const float* __restrict__ mbuf,
    float* __restrict__ out)
{
    int b = blockIdx.x, tid = threadIdx.x;
    for (int f = tid; f < 24 * 128; f += 256) {
        int p = f >> 7, c = f & 127;
        int axis = p >> 3, idx = p & 7;
        float sum = 0.f;
        for (int t = 0; t < 64; t++) {
            int node;
            if (axis == 0)      node = idx * 64 + t;
            else if (axis == 1) node = (t >> 3) * 64 + idx * 8 + (t & 7);
            else                node = t * 8 + idx;
            sum += b2f(xbuf[(size_t)(b * S3 + node) * Cc + c]) * mbuf[b * S3 + node];
        }
        out[(size_t)b * 26 * Cc + p * Cc + c] = sum * (1.f / 64.f);
    }
}

// ---------------------------------------------------------------------------
// k_tf2: full transformer per batch element (register-tiled VALU, unchanged)
// ---------------------------------------------------------------------------
__global__ __launch_bounds__(384, 3) void k_tf2(
    const int* __restrict__ xx, const float* __restrict__ ss,
    const float4* __restrict__ WactP, const float* __restrict__ bact,
    const float4* __restrict__ WqkvP, const float* __restrict__ bqkv,
    const float4* __restrict__ WoP, const float* __restrict__ bo,
    const float* __restrict__ ln1g, const float* __restrict__ ln1b,
    const float* __restrict__ ln2g, const float* __restrict__ ln2b,
    const float4* __restrict__ W1P, const float* __restrict__ b1v,
    const float4* __restrict__ W2P, const float* __restrict__ b2v,
    const float* __restrict__ Wsc, const float* __restrict__ bsc,
    float* __restrict__ out)
{
    __shared__ float As[TT * 132];
    __shared__ float Hs[TT * 132];
    __shared__ float Qs[TT * 388];
    __shared__ float Fs[TT * 516];
    __shared__ float Att[60 * 16];
    __shared__ float mu_s[TT], rs_s[TT];

    int b = blockIdx.x, tid = threadIdx.x;

    const int* xa = xx + (size_t)b * Tsz * S3 + S3;
    for (int f = tid; f < TT * 512; f += 384) {
        int t = f >> 9, s = f & 511;
        Fs[t * 516 + s] = (float)xa[t * 512 + s];
    }
    __syncthreads();

    {
        int cp = tid & 63, g = tid >> 6;
        int nt = (g < 3) ? 3 : 2;
        float acc[3][2] = {};
        for (int k4 = 0; k4 < 128; k4++) {
            float4 wa = WactP[k4 * 128 + cp];
            float4 wb = WactP[k4 * 128 + cp + 64];
#pragma unroll
            for (int it = 0; it < 3; it++) if (it < nt) {
                int t = g + it * 6;
                float4 xv = *(const float4*)(Fs + t * 516 + k4 * 4);
                acc[it][0] += dot4(xv, wa);
                acc[it][1] += dot4(xv, wb);
            }
        }
        float b0 = bact[cp], b1b = bact[cp + 64];
        for (int it = 0; it < nt; it++) {
            int t = g + it * 6;
            As[t * 132 + cp]      = acc[it][0] + b0;
            As[t * 132 + cp + 64] = acc[it][1] + b1b;
        }
    }
    __syncthreads();

    for (int l = 0; l < 2; l++) {
        const float* bq  = bqkv + l * 384;
        const float* bol = bo + l * 128;
        const float* g1  = ln1g + l * 128; const float* be1 = ln1b + l * 128;
        const float* g2  = ln2g + l * 128; const float* be2 = ln2b + l * 128;
        const float* b1l = b1v + l * 512;  const float* b2l = b2v + l * 128;

        {
            int wv = tid >> 6, ln = tid & 63;
            for (int r = wv; r < TT; r += 6) {
                float2 v = *(const float2*)(As + r * 132 + ln * 2);
                float s = v.x + v.y, q = v.x * v.x + v.y * v.y;
                for (int off = 32; off; off >>= 1) {
                    s += __shfl_xor(s, off, 64);
                    q += __shfl_xor(q, off, 64);
                }
                if (ln == 0) {
                    float mu = s * (1.f / 128.f);
                    mu_s[r] = mu;
                    rs_s[r] = rsqrtf(q * (1.f / 128.f) - mu * mu + EPSv);
                }
            }
        }
        __syncthreads();
        for (int f = tid; f < TT * 128; f += 384) {
            int t = f >> 7, co = f & 127;
            Hs[t * 132 + co] = (As[t * 132 + co] - mu_s[t]) * rs_s[t] * g1[co] + be1[co];
        }
        __syncthreads();

        {
            int cp = tid % 192, g = tid / 192;
            int t0 = g * 8, nt = g ? 7 : 8;
            int ra = l * 384 + cp, rb = ra + 192;
            float acc[8][2] = {};
            for (int k4 = 0; k4 < 32; k4++) {
                float4 wa = WqkvP[k4 * 768 + ra];
                float4 wb = WqkvP[k4 * 768 + rb];
#pragma unroll
                for (int it = 0; it < 8; it++) if (it < nt) {
                    float4 xv = *(const float4*)(Hs + (t0 + it) * 132 + k4 * 4);
                    acc[it][0] += dot4(xv, wa);
                    acc[it][1] += dot4(xv, wb);
                }
            }
            float b0 = bq[cp], b1b = bq[cp + 192];
            for (int it = 0; it < nt; it++) {
                Qs[(t0 + it) * 388 + cp]       = acc[it][0] + b0;
                Qs[(t0 + it) * 388 + cp + 192] = acc[it][1] + b1b;
            }
        }
        __syncthreads();

        if (tid < 60) {
            int h = tid / 15, tq = tid % 15;
            const float* qp = Qs + tq * 388 + h * 32;
            float sc[TT];
            float mx = -1e30f;
#pragma unroll
            for (int tk = 0; tk < TT; tk++) {
                const float* kp = Qs + tk * 388 + 128 + h * 32;
                float d = 0.f;
#pragma unroll
                for (int u = 0; u < 32; u += 4)
                    d += dot4(*(const float4*)(qp + u), *(const float4*)(kp + u));
                d *= 0.17677669529663689f;
                sc[tk] = d; mx = fmaxf(mx, d);
            }
            float sum = 0.f;
#pragma unroll
            for (int tk = 0; tk < TT; tk++) { float e = __expf(sc[tk] - mx); sc[tk] = e; sum += e; }
            float r = 1.f / sum;
#pragma unroll
            for (int tk = 0; tk < TT; tk++) Att[tid * 16 + tk] = sc[tk] * r;
        }
        __syncthreads();

        for (int f = tid; f < TT * 128; f += 384) {
            int t = f >> 7, co = f & 127;
            int h = co >> 5;
            const float* ap = Att + (h * 15 + t) * 16;
            const float* vp = Qs + 256 + co;
            float acc = 0.f;
#pragma unroll
            for (int tk = 0; tk < TT; tk++) acc += ap[tk] * vp[tk * 388];
            Hs[t * 132 + co] = acc;
        }
        __syncthreads();

        {
            int cp = tid & 63, g = tid >> 6;
            int nt = (g < 3) ? 3 : 2;
            int ra = l * 128 + cp, rb = ra + 64;
            float acc[3][2] = {};
            for (int k4 = 0; k4 < 32; k4++) {
                float4 wa = WoP[k4 * 256 + ra];
                float4 wb = WoP[k4 * 256 + rb];
#pragma unroll
                for (int it = 0; it < 3; it++) if (it < nt) {
                    int t = g + it * 6;
                    float4 xv = *(const float4*)(Hs + t * 132 + k4 * 4);
                    acc[it][0] += dot4(xv, wa);
                    acc[it][1] += dot4(xv, wb);
                }
            }
            float b0 = bol[cp], b1b = bol[cp + 64];
            for (int it = 0; it < nt; it++) {
                int t = g + it * 6;
                As[t * 132 + cp]      += acc[it][0] + b0;
                As[t * 132 + cp + 64] += acc[it][1] + b1b;
            }
        }
        __syncthreads();

        {
            int wv = tid >> 6, ln = tid & 63;
            for (int r = wv; r < TT; r += 6) {
                float2 v = *(const float2*)(As + r * 132 + ln * 2);
                float s = v.x + v.y, q = v.x * v.x + v.y * v.y;
                for (int off = 32; off; off >>= 1) {
                    s += __shfl_xor(s, off, 64);
                    q += __shfl_xor(q, off, 64);
                }
                if (ln == 0) {
                    float mu = s * (1.f / 128.f);
                    mu_s[r] = mu;
                    rs_s[r] = rsqrtf(q * (1.f / 128.f) - mu * mu + EPSv);
                }
            }
        }
        __syncthreads();
        for (int f = tid; f < TT * 128; f += 384) {
            int t = f >> 7, co = f & 127;
            Hs[t * 132 + co] = (As[t * 132 + co] - mu_s[t]) * rs_s[t] * g2[co] + be2[co];
        }
        __syncthreads();

        {
            int cp = tid & 127, g = tid >> 7;
            int r0 = l * 512 + cp;
            float acc[5][4] = {};
            for (int k4 = 0; k4 < 32; k4++) {
                float4 w0 = W1P[k4 * 1024 + r0];
                float4 w1 = W1P[k4 * 1024 + r0 + 128];
                float4 w2 = W1P[k4 * 1024 + r0 + 256];
                float4 w3 = W1P[k4 * 1024 + r0 + 384];
#pragma unroll
                for (int it = 0; it < 5; it++) {
                    int t = g + it * 3;
                    float4 xv = *(const float4*)(Hs + t * 132 + k4 * 4);
                    acc[it][0] += dot4(xv, w0);
                    acc[it][1] += dot4(xv, w1);
                    acc[it][2] += dot4(xv, w2);
                    acc[it][3] += dot4(xv, w3);
                }
            }
            float bb0 = b1l[cp], bb1 = b1l[cp + 128], bb2 = b1l[cp + 256], bb3 = b1l[cp + 384];
            for (int it = 0; it < 5; it++) {
                int t = g + it * 3;
                Fs[t * 516 + cp]       = fmaxf(acc[it][0] + bb0, 0.f);
                Fs[t * 516 + cp + 128] = fmaxf(acc[it][1] + bb1, 0.f);
                Fs[t * 516 + cp + 256] = fmaxf(acc[it][2] + bb2, 0.f);
                Fs[t * 516 + cp + 384] = fmaxf(acc[it][3] + bb3, 0.f);
            }
        }
        __syncthreads();

        {
            int cp = tid & 63, g = tid >> 6;
            int nt = (g < 3) ? 3 : 2;
            int ra = l * 128 + cp, rb = ra + 64;
            float acc[3][2] = {};
            for (int k4 = 0; k4 < 128; k4++) {
                float4 wa = W2P[k4 * 256 + ra];
                float4 wb = W2P[k4 * 256 + rb];
#pragma unroll
                for (int it = 0; it < 3; it++) if (it < nt) {
                    int t = g + it * 6;
                    float4 xv = *(const float4*)(Fs + t * 516 + k4 * 4);
                    acc[it][0] += dot4(xv, wa);
                    acc[it][1] += dot4(xv, wb);
                }
            }
            float b0 = b2l[cp], b1b = b2l[cp + 64];
            for (int it = 0; it < nt; it++) {
                int t = g + it * 6;
                As[t * 132 + cp]      += acc[it][0] + b0;
                As[t * 132 + cp + 64] += acc[it][1] + b1b;
            }
        }
        __syncthreads();
    }

    if (tid < 128) {
        float s = 0.f;
#pragma unroll
        for (int t = 0; t < TT; t++) s += As[t * 132 + tid];
        out[(size_t)b * 26 * Cc + 24 * Cc + tid] = s * (1.f / 15.f);
    } else if (tid < 256) {
        int co = tid - 128;
        float v = ss[b] * Wsc[co] + bsc[co];
        out[(size_t)b * 26 * Cc + 25 * Cc + co] = fmaxf(v, 0.f);
    }
}

// ---------------------------------------------------------------------------
extern "C" void kernel_launch(void* const* d_in, const int* in_sizes, int n_in,
                              void* d_out, int out_size, void* d_ws, size_t ws_size,
                              hipStream_t stream)
{
    (void)in_sizes; (void)n_in; (void)out_size; (void)ws_size;
    const int*   xx   = (const int*)d_in[0];
    const float* ss   = (const float*)d_in[1];
    const float* Win  = (const float*)d_in[2];
    const float* b_in = (const float*)d_in[3];
    const float* Wl   = (const float*)d_in[4];
    const float* bl   = (const float*)d_in[5];
    const float* Wr   = (const float*)d_in[6];
    const float* lng  = (const float*)d_in[7];
    const float* lnb  = (const float*)d_in[8];
    const float* Wqkv = (const float*)d_in[9];
    const float* bqkv = (const float*)d_in[10];
    const float* Wo   = (const float*)d_in[11];
    const float* bo   = (const float*)d_in[12];
    const float* ln1g = (const float*)d_in[13];
    const float* ln1b = (const float*)d_in[14];
    const float* ln2g = (const float*)d_in[15];
    const float* ln2b = (const float*)d_in[16];
    const float* W1   = (const float*)d_in[17];
    const float* b1   = (const float*)d_in[18];
    const float* W2   = (const float*)d_in[19];
    const float* b2   = (const float*)d_in[20];
    const float* Wact = (const float*)d_in[21];
    const float* bact = (const float*)d_in[22];
    const float* Wsc  = (const float*)d_in[23];
    const float* bsc  = (const float*)d_in[24];
    float* out = (float*)d_out;

    char* ws = (char*)d_ws;
    size_t off = 0;
    bf16*  xbuf = (bf16*)(ws + off);  off += (size_t)Bsz * S3 * Cc * 2;
    float* sA   = (float*)(ws + off); off += (size_t)Bsz * Cc * 4;
    float* sB   = (float*)(ws + off); off += (size_t)Bsz * Cc * 4;
    float* invb = (float*)(ws + off); off += (size_t)Bsz * 4;
    float* mbuf = (float*)(ws + off); off += (size_t)Bsz * S3 * 4;
    float* WactT = (float*)(ws + off); off += 512 * 128 * 4;
    float* WqkvT = (float*)(ws + off); off += 768 * 128 * 4;
    float* WoT   = (float*)(ws + off); off += 256 * 128 * 4;
    float* W1T   = (float*)(ws + off); off += 1024 * 128 * 4;
    float* W2T   = (float*)(ws + off); off += 256 * 512 * 4;
    float* WlT   = (float*)(ws + off); off += 384 * 128 * 4;
    ushort* dbuf = (ushort*)(ws + off); off += (size_t)Bsz * 16384 * 2;  // 16.8 MB

    // weight pre-transposes (k-major float4-packed)
    k_tpack<<<dim3(16, 4),  256, 0, stream>>>(Wact, WactT, 128, 512);
    k_tpack<<<dim3(4, 24),  256, 0, stream>>>(Wqkv, WqkvT, 768, 128);
    k_tpack<<<dim3(4, 8),   256, 0, stream>>>(Wo,   WoT,   256, 128);
    k_tpack<<<dim3(4, 32),  256, 0, stream>>>(W1,   W1T,  1024, 128);
    k_tpack<<<dim3(16, 8),  256, 0, stream>>>(W2,   W2T,   256, 512);
    k_tpack<<<dim3(4, 12),  256, 0, stream>>>(Wl,   WlT,   384, 128);

    k_init<<<Bsz, 512, 0, stream>>>(xx, ss, Win, b_in, xbuf, sA, invb, mbuf);

    // layer 0
    k_dw<<<Bsz, 256, 0, stream>>>(Wl, Wr, invb, dbuf);
    hipMemsetAsync(sB, 0, (size_t)Bsz * Cc * 4, stream);
    k_gnn<<<Bsz * 8, 256, 0, stream>>>(xbuf, sA, invb, dbuf,
                                       (const float4*)WlT, 0, bl,
                                       lng, lnb, mbuf, sB, 1);
    // layer 1
    k_dw<<<Bsz, 256, 0, stream>>>(Wl + 16384, Wr + 16384, invb, dbuf);
    hipMemsetAsync(sA, 0, (size_t)Bsz * Cc * 4, stream);
    k_gnn<<<Bsz * 8, 256, 0, stream>>>(xbuf, sB, invb, dbuf,
                                       (const float4*)WlT, 128, bl + 128,
                                       lng, lnb, mbuf, sA, 1);
    // layer 2
    k_dw<<<Bsz, 256, 0, stream>>>(Wl + 32768, Wr + 32768, invb, dbuf);
    k_gnn<<<Bsz * 8, 256, 0, stream>>>(xbuf, sA, invb, dbuf,
                                       (const float4*)WlT, 256, bl + 256,
                                       lng, lnb, mbuf, sB, 0);

    k_pool<<<Bsz, 256, 0, stream>>>(xbuf, mbuf, out);

    k_tf2<<<Bsz, 384, 0, stream>>>(xx, ss,
                                   (const float4*)WactT, bact,
                                   (const float4*)WqkvT, bqkv,
                                   (const float4*)WoT,   bo,
                                   ln1g, ln1b, ln2g, ln2b,
                                   (const float4*)W1T,   b1,
                                   (const float4*)W2T,   b2,
                                   Wsc, bsc, out);
}

// Round 4
// 595.640 us; speedup vs baseline: 4.6932x; 1.4918x over previous
//
#include <hip/hip_runtime.h>
#include <hip/hip_bf16.h>
#include <string.h>

typedef __hip_bfloat16 bf16;
typedef __attribute__((ext_vector_type(8))) short short8;
typedef __attribute__((ext_vector_type(4))) float f32x4;

#define Bsz 512
#define S3  512
#define Tsz 16
#define Cc  128
#define TT  15
#define EPSv 1e-5f

__device__ __forceinline__ float u2f(unsigned short u) {
    return __uint_as_float(((unsigned)u) << 16);
}
__device__ __forceinline__ float b2f(bf16 v) { return __bfloat162float(v); }
__device__ __forceinline__ bf16  f2b(float v) { return __float2bfloat16(v); }
__device__ __forceinline__ unsigned short f2bu(float v) {
    bf16 h = __float2bfloat16(v);
    unsigned short u; memcpy(&u, &h, 2); return u;
}
__device__ __forceinline__ unsigned packbf(float a, float b) {
    return (unsigned)f2bu(a) | ((unsigned)f2bu(b) << 16);
}
__device__ __forceinline__ float dot4(float4 a, float4 b) {
    return a.x*b.x + a.y*b.y + a.z*b.z + a.w*b.w;
}

// ---------------------------------------------------------------------------
// k_tpack: src (NR x NK) row-major fp32 -> float4-packed k-major (for k_gnn base)
// ---------------------------------------------------------------------------
__global__ __launch_bounds__(256) void k_tpack(const float* __restrict__ src,
                                               float* __restrict__ dst,
                                               int NR, int NK)
{
    __shared__ float tile[32][33];
    int k0 = blockIdx.x * 32, r0 = blockIdx.y * 32;
    int lr = threadIdx.x >> 5, lk = threadIdx.x & 31;
    for (int i = lr; i < 32; i += 8)
        tile[i][lk] = src[(size_t)(r0 + i) * NK + k0 + lk];
    __syncthreads();
    int c = threadIdx.x & 31, k4 = threadIdx.x >> 5;
    float4 v;
    v.x = tile[c][k4 * 4 + 0]; v.y = tile[c][k4 * 4 + 1];
    v.z = tile[c][k4 * 4 + 2]; v.w = tile[c][k4 * 4 + 3];
    ((float4*)dst)[(size_t)(k0 / 4 + k4) * NR + r0 + c] = v;
}

// ---------------------------------------------------------------------------
// k_cvt: fp32 -> bf16 elementwise (layout preserved), n % 4 == 0
// ---------------------------------------------------------------------------
__global__ __launch_bounds__(256) void k_cvt(const float* __restrict__ src,
                                             ushort* __restrict__ dst, int n4)
{
    int i = blockIdx.x * 256 + threadIdx.x;
    if (i < n4) {
        float4 v = ((const float4*)src)[i];
        ushort4 o;
        o.x = f2bu(v.x); o.y = f2bu(v.y); o.z = f2bu(v.z); o.w = f2bu(v.w);
        ((ushort4*)dst)[i] = o;
    }
}

// ---------------------------------------------------------------------------
// k_dw: per-batch combined GNN weight d = Wr - inv*Wl -> bf16 (128x128 row-major)
// ---------------------------------------------------------------------------
__global__ __launch_bounds__(256) void k_dw(
    const float* __restrict__ Wl, const float* __restrict__ Wr,
    const float* __restrict__ invbuf, ushort* __restrict__ dbuf)
{
    int b = blockIdx.x;
    float inv = invbuf[b];
    ushort4* dst = (ushort4*)(dbuf + (size_t)b * 16384);
    const float4* wl4 = (const float4*)Wl;
    const float4* wr4 = (const float4*)Wr;
    for (int f = threadIdx.x; f < 4096; f += 256) {
        float4 a = wl4[f];
        float4 r = wr4[f];
        ushort4 o;
        o.x = f2bu(r.x - inv * a.x); o.y = f2bu(r.y - inv * a.y);
        o.z = f2bu(r.z - inv * a.z); o.w = f2bu(r.w - inv * a.w);
        dst[f] = o;
    }
}

// ---------------------------------------------------------------------------
// k_init: features -> lin_in -> x0 (bf16), mask, n->inv, s0
// ---------------------------------------------------------------------------
__global__ __launch_bounds__(512) void k_init(
    const int* __restrict__ xx, const float* __restrict__ ss,
    const float* __restrict__ Win, const float* __restrict__ b_in,
    bf16* __restrict__ xbuf, float* __restrict__ sbuf,
    float* __restrict__ invbuf, float* __restrict__ mbuf)
{
    __shared__ float sred[8 * 128];
    __shared__ float scnt[8];
    int b = blockIdx.x, tid = threadIdx.x;
    int g = tid >> 6, cp = tid & 63;
    int co0 = 2 * cp, co1 = 2 * cp + 1;
    const int* x0 = xx + (size_t)b * Tsz * S3;
    float f4c = ss[b] * (1.0f / 8.0f);
    float a0 = Win[co0*5+0], a1 = Win[co0*5+1], a2 = Win[co0*5+2], a3 = Win[co0*5+3], a4 = Win[co0*5+4];
    float c0 = Win[co1*5+0], c1 = Win[co1*5+1], c2 = Win[co1*5+2], c3 = Win[co1*5+3], c4 = Win[co1*5+4];
    float ba = b_in[co0], bc = b_in[co1];
    unsigned* xo = (unsigned*)xbuf;

    float sp0 = 0.f, sp1 = 0.f; int cnt = 0;
    for (int node = g; node < S3; node += 8) {
        int f0 = x0[node];
        float m = (f0 != 0) ? 1.f : 0.f;
        float ci = (float)(node >> 6) * (1.f / 7.f);
        float cj = (float)((node >> 3) & 7) * (1.f / 7.f);
        float ck = (float)(node & 7) * (1.f / 7.f);
        float ft = (float)f0 * 0.5f;
        float v0 = ba + ci * a0 + cj * a1 + ck * a2 + ft * a3 + f4c * a4;
        float v1 = bc + ci * c0 + cj * c1 + ck * c2 + ft * c3 + f4c * c4;
        xo[(size_t)(b * S3 + node) * 64 + cp] = packbf(v0, v1);
        sp0 += v0 * m; sp1 += v1 * m;
        cnt += (f0 != 0);
        if (cp == 0) mbuf[b * S3 + node] = m;
    }
    sred[g * 128 + co0] = sp0;
    sred[g * 128 + co1] = sp1;
    if (cp == 0) scnt[g] = (float)cnt;
    __syncthreads();
    if (tid < 128) {
        float s = 0.f;
#pragma unroll
        for (int gg = 0; gg < 8; gg++) s += sred[gg * 128 + tid];
        sbuf[b * Cc + tid] = s;
    }
    if (tid == 0) {
        float n = 0.f;
#pragma unroll
        for (int gg = 0; gg < 8; gg++) n += scnt[gg];
        invbuf[b] = (n > 1.f) ? 1.f / (n - 1.f) : 0.f;
    }
}

// ---------------------------------------------------------------------------
// k_gnn (MFMA): one SAGE layer (unchanged from round 3)
// ---------------------------------------------------------------------------
__global__ __launch_bounds__(256) void k_gnn(
    bf16* __restrict__ xbuf,
    const float* __restrict__ sIn, const float* __restrict__ invbuf,
    const ushort* __restrict__ dbuf,
    const float4* __restrict__ WlP, int lbase, const float* __restrict__ blv,
    const float* __restrict__ lng, const float* __restrict__ lnb,
    const float* __restrict__ mbuf,
    float* __restrict__ sout, int acc_s)
{
    __shared__ char raw[(64 * 136 + 128 * 136) * 2];
    __shared__ float sinv[128];
    __shared__ float sbase[128];
    __shared__ float stats[128];
    __shared__ float sred[512];

    ushort* Abuf = (ushort*)raw;
    ushort* Bbuf = Abuf + 64 * 136;

    int tid = threadIdx.x;
    int b = blockIdx.x & 511;
    int node0 = (blockIdx.x >> 9) * 64;
    float inv = invbuf[b];

    const ushort4* xg4 = (const ushort4*)(xbuf + (size_t)(b * S3 + node0) * Cc);
    for (int f = tid; f < 2048; f += 256) {
        int node = f >> 5, pos = f & 31;
        ((ushort4*)(Abuf + node * 136))[pos] = xg4[f];
    }
    const ushort4* dg4 = (const ushort4*)(dbuf + (size_t)b * 16384);
    for (int f = tid; f < 4096; f += 256) {
        int row = f >> 5, pos = f & 31;
        ((ushort4*)(Bbuf + row * 136))[pos] = dg4[f];
    }
    if (tid < 128) sinv[tid] = sIn[b * Cc + tid] * inv;
    __syncthreads();

    if (tid < 128) {
        float acc = blv[tid];
        for (int k4 = 0; k4 < 32; k4++) {
            float4 w = WlP[k4 * 384 + lbase + tid];
            float4 s4 = *(const float4*)(sinv + k4 * 4);
            acc += dot4(s4, w);
        }
        sbase[tid] = acc;
    }

    int wv = tid >> 6, lane = tid & 63;
    int ml = lane & 15, quad = lane >> 4;
    const ushort* arow  = Abuf + (wv * 16 + ml) * 136 + quad * 8;
    const ushort* bbase = Bbuf + ml * 136 + quad * 8;

    f32x4 acc[8];
#pragma unroll
    for (int t = 0; t < 8; t++) acc[t] = (f32x4){0.f, 0.f, 0.f, 0.f};

#pragma unroll
    for (int ks = 0; ks < 4; ks++) {
        short8 a = *(const short8*)(arow + ks * 32);
        const ushort* bk = bbase + ks * 32;
#pragma unroll
        for (int t = 0; t < 8; t++) {
            short8 bfr = *(const short8*)(bk + t * (16 * 136));
            acc[t] = __builtin_amdgcn_mfma_f32_16x16x32_bf16(a, bfr, acc[t], 0, 0, 0);
        }
    }
    __syncthreads();

    float* hbuf = (float*)raw;
#pragma unroll
    for (int t = 0; t < 8; t++) {
#pragma unroll
        for (int r = 0; r < 4; r++) {
            int row = wv * 16 + quad * 4 + r;
            int col = t * 16 + ml;
            hbuf[row * 129 + col] = fmaxf(acc[t][r] + sbase[col], 0.f);
        }
    }
    __syncthreads();

    if (tid < 64) {
        const float* row = hbuf + tid * 129;
        float s = 0.f, s2 = 0.f;
        for (int j = 0; j < 128; j++) { float v = row[j]; s += v; s2 += v * v; }
        float mu = s * (1.f / 128.f);
        float var = s2 * (1.f / 128.f) - mu * mu;
        stats[tid] = mu;
        stats[64 + tid] = rsqrtf(var + EPSv);
    }
    __syncthreads();

    int co0 = tid & 63, co1 = co0 + 64, g = tid >> 6;
    float gg0 = lng[co0], gg1 = lng[co1], be0 = lnb[co0], be1 = lnb[co1];
    float sp0 = 0.f, sp1 = 0.f;
    bf16* xo = xbuf + (size_t)(b * S3 + node0) * Cc;
#pragma unroll
    for (int i = 0; i < 16; i++) {
        int node = g * 16 + i;
        float mu = stats[node], rs = stats[64 + node];
        float y0 = (hbuf[node * 129 + co0] - mu) * rs * gg0 + be0;
        float y1 = (hbuf[node * 129 + co1] - mu) * rs * gg1 + be1;
        xo[node * Cc + co0] = f2b(y0);
        xo[node * Cc + co1] = f2b(y1);
        float m = mbuf[b * S3 + node0 + node];
        sp0 += y0 * m;
        sp1 += y1 * m;
    }
    if (acc_s) {
        sred[g * 128 + co0] = sp0;
        sred[g * 128 + co1] = sp1;
        __syncthreads();
        if (tid < 128) {
            float t = sred[tid] + sred[128 + tid] + sred[256 + tid] + sred[384 + tid];
            atomicAdd(&sout[b * Cc + tid], t);
        }
    }
}

// ---------------------------------------------------------------------------
// k_pool
// ---------------------------------------------------------------------------
__global__ __launch_bounds__(256) void k_pool(
    const bf16* __restrict__ xbuf, const float* __restrict__ mbuf,
    float* __restrict__ out)
{
    int b = blockIdx.x, tid = threadIdx.x;
    for (int f = tid; f < 24 * 128; f += 256) {
        int p = f >> 7, c = f & 127;
        int axis = p >> 3, idx = p & 7;
        float sum = 0.f;
        for (int t = 0; t < 64; t++) {
            int node;
            if (axis == 0)      node = idx * 64 + t;
            else if (axis == 1) node = (t >> 3) * 64 + idx * 8 + (t & 7);
            else                node = t * 8 + idx;
            sum += b2f(xbuf[(size_t)(b * S3 + node) * Cc + c]) * mbuf[b * S3 + node];
        }
        out[(size_t)b * 26 * Cc + p * Cc + c] = sum * (1.f / 64.f);
    }
}

// ---------------------------------------------------------------------------
// k_tf3: transformer with bf16 MFMA GEMMs. 256 threads (4 waves) per batch.
// A-operand: bf16 LDS rows [token][k], m=lane&15, k=quad*8+j (validated in k_gnn).
// B-operand: bf16 global row-major [cout][k], n=lane&15 (same k mapping).
// C: col=lane&15, row=quad*4+reg; row 15 (pad token) discarded.
// ---------------------------------------------------------------------------
__global__ __launch_bounds__(256) void k_tf3(
    const int* __restrict__ xx, const float* __restrict__ ss,
    const ushort* __restrict__ WactB, const float* __restrict__ bact,
    const ushort* __restrict__ WqkvB, const float* __restrict__ bqkv,
    const ushort* __restrict__ WoB, const float* __restrict__ bo,
    const float* __restrict__ ln1g, const float* __restrict__ ln1b,
    const float* __restrict__ ln2g, const float* __restrict__ ln2b,
    const ushort* __restrict__ W1B, const float* __restrict__ b1v,
    const ushort* __restrict__ W2B, const float* __restrict__ b2v,
    const float* __restrict__ Wsc, const float* __restrict__ bsc,
    float* __restrict__ out)
{
    __shared__ float  As[TT * 132];     // fp32 residual stream
    __shared__ float  Qs[TT * 388];     // fp32 q|k|v for attention
    __shared__ ushort Ab[16 * 136];     // bf16 LN output (A operand, K=128)
    __shared__ ushort Hs[16 * 136];     // bf16 attn output (A operand, K=128)
    __shared__ ushort Fs[16 * 520];     // bf16 K=512 A operand (embed stage / ff1 out)
    __shared__ float  Att[60 * 16];
    __shared__ float  mu_s[TT], rs_s[TT];

    int b = blockIdx.x, tid = threadIdx.x;
    int wv = tid >> 6, lane = tid & 63;
    int ml = lane & 15, quad = lane >> 4;

    // ---- stage action frames (0..2 ints, exact in bf16) into Fs
    const int* xa = xx + (size_t)b * Tsz * S3 + S3;
    for (int f = tid; f < TT * 512; f += 256) {
        int t = f >> 9, s = f & 511;
        Fs[t * 520 + s] = f2bu((float)xa[t * 512 + s]);
    }
    __syncthreads();

    // ---- embed: As = Fs @ WactB^T + bact   (K=512, N=128; wave: 2 n-tiles)
    {
        f32x4 acc[2];
#pragma unroll
        for (int i = 0; i < 2; i++) acc[i] = (f32x4){0.f, 0.f, 0.f, 0.f};
        const ushort* ar = Fs + ml * 520 + quad * 8;
        for (int ks = 0; ks < 16; ks++) {
            short8 a = *(const short8*)(ar + ks * 32);
#pragma unroll
            for (int i = 0; i < 2; i++) {
                int n0 = (wv * 2 + i) * 16;
                short8 bfr = *(const short8*)(WactB + (size_t)(n0 + ml) * 512 + quad * 8 + ks * 32);
                acc[i] = __builtin_amdgcn_mfma_f32_16x16x32_bf16(a, bfr, acc[i], 0, 0, 0);
            }
        }
#pragma unroll
        for (int i = 0; i < 2; i++) {
            int col = (wv * 2 + i) * 16 + ml;
            float bb = bact[col];
#pragma unroll
            for (int r = 0; r < 4; r++) {
                int row = quad * 4 + r;
                if (row < TT) As[row * 132 + col] = acc[i][r] + bb;
            }
        }
    }
    __syncthreads();

    for (int l = 0; l < 2; l++) {
        const float* bq  = bqkv + l * 384;
        const float* bol = bo + l * 128;
        const float* g1  = ln1g + l * 128; const float* be1 = ln1b + l * 128;
        const float* g2  = ln2g + l * 128; const float* be2 = ln2b + l * 128;
        const float* b1l = b1v + l * 512;  const float* b2l = b2v + l * 128;

        // ---- LN1 -> Ab (bf16)
        for (int r = wv; r < TT; r += 4) {
            float2 v = *(const float2*)(As + r * 132 + lane * 2);
            float s = v.x + v.y, q = v.x * v.x + v.y * v.y;
            for (int off = 32; off; off >>= 1) {
                s += __shfl_xor(s, off, 64);
                q += __shfl_xor(q, off, 64);
            }
            if (lane == 0) {
                float mu = s * (1.f / 128.f);
                mu_s[r] = mu;
                rs_s[r] = rsqrtf(q * (1.f / 128.f) - mu * mu + EPSv);
            }
        }
        __syncthreads();
        for (int f = tid; f < TT * 64; f += 256) {
            int t = f >> 6, cp = f & 63;
            float mu = mu_s[t], rs = rs_s[t];
            float x0 = (As[t * 132 + 2 * cp]     - mu) * rs * g1[2 * cp]     + be1[2 * cp];
            float x1 = (As[t * 132 + 2 * cp + 1] - mu) * rs * g1[2 * cp + 1] + be1[2 * cp + 1];
            ((unsigned*)(Ab + t * 136))[cp] = packbf(x0, x1);
        }
        __syncthreads();

        // ---- qkv: Qs = Ab @ Wqkv^T + bq   (K=128, N=384; wave: 6 n-tiles)
        {
            short8 a[4];
            const ushort* ar = Ab + ml * 136 + quad * 8;
#pragma unroll
            for (int ks = 0; ks < 4; ks++) a[ks] = *(const short8*)(ar + ks * 32);
#pragma unroll
            for (int i = 0; i < 6; i++) {
                int n0 = (wv * 6 + i) * 16;
                f32x4 acc = (f32x4){0.f, 0.f, 0.f, 0.f};
                const ushort* wb = WqkvB + (size_t)(l * 384 + n0 + ml) * 128 + quad * 8;
#pragma unroll
                for (int ks = 0; ks < 4; ks++) {
                    short8 bfr = *(const short8*)(wb + ks * 32);
                    acc = __builtin_amdgcn_mfma_f32_16x16x32_bf16(a[ks], bfr, acc, 0, 0, 0);
                }
                int col = n0 + ml;
                float bb = bq[col];
#pragma unroll
                for (int r = 0; r < 4; r++) {
                    int row = quad * 4 + r;
                    if (row < TT) Qs[row * 388 + col] = acc[r] + bb;
                }
            }
        }
        __syncthreads();

        // ---- attention scores + softmax (60 threads, fp32)
        if (tid < 60) {
            int h = tid / 15, tq = tid % 15;
            const float* qp = Qs + tq * 388 + h * 32;
            float sc[TT];
            float mx = -1e30f;
#pragma unroll
            for (int tk = 0; tk < TT; tk++) {
                const float* kp = Qs + tk * 388 + 128 + h * 32;
                float d = 0.f;
#pragma unroll
                for (int u = 0; u < 32; u += 4)
                    d += dot4(*(const float4*)(qp + u), *(const float4*)(kp + u));
                d *= 0.17677669529663689f;
                sc[tk] = d; mx = fmaxf(mx, d);
            }
            float sum = 0.f;
#pragma unroll
            for (int tk = 0; tk < TT; tk++) { float e = __expf(sc[tk] - mx); sc[tk] = e; sum += e; }
            float r = 1.f / sum;
#pragma unroll
            for (int tk = 0; tk < TT; tk++) Att[tid * 16 + tk] = sc[tk] * r;
        }
        __syncthreads();

        // ---- o = att @ v -> Hs (bf16)
        for (int f = tid; f < TT * 64; f += 256) {
            int t = f >> 6, cp = f & 63;
            int c0 = 2 * cp, c1 = 2 * cp + 1;
            int h = c0 >> 5;
            const float* ap = Att + (h * 15 + t) * 16;
            const float* vp = Qs + 256;
            float a0 = 0.f, a1 = 0.f;
#pragma unroll
            for (int tk = 0; tk < TT; tk++) {
                float w = ap[tk];
                a0 += w * vp[tk * 388 + c0];
                a1 += w * vp[tk * 388 + c1];
            }
            ((unsigned*)(Hs + t * 136))[cp] = packbf(a0, a1);
        }
        __syncthreads();

        // ---- proj + residual: As += Hs @ Wo^T + bo   (K=128, N=128; wave: 2 tiles)
        {
            short8 a[4];
            const ushort* ar = Hs + ml * 136 + quad * 8;
#pragma unroll
            for (int ks = 0; ks < 4; ks++) a[ks] = *(const short8*)(ar + ks * 32);
#pragma unroll
            for (int i = 0; i < 2; i++) {
                int n0 = (wv * 2 + i) * 16;
                f32x4 acc = (f32x4){0.f, 0.f, 0.f, 0.f};
                const ushort* wb = WoB + (size_t)(l * 128 + n0 + ml) * 128 + quad * 8;
#pragma unroll
                for (int ks = 0; ks < 4; ks++) {
                    short8 bfr = *(const short8*)(wb + ks * 32);
                    acc = __builtin_amdgcn_mfma_f32_16x16x32_bf16(a[ks], bfr, acc, 0, 0, 0);
                }
                int col = n0 + ml;
                float bb = bol[col];
#pragma unroll
                for (int r = 0; r < 4; r++) {
                    int row = quad * 4 + r;
                    if (row < TT) As[row * 132 + col] += acc[r] + bb;
                }
            }
        }
        __syncthreads();

        // ---- LN2 -> Ab (bf16)
        for (int r = wv; r < TT; r += 4) {
            float2 v = *(const float2*)(As + r * 132 + lane * 2);
            float s = v.x + v.y, q = v.x * v.x + v.y * v.y;
            for (int off = 32; off; off >>= 1) {
                s += __shfl_xor(s, off, 64);
                q += __shfl_xor(q, off, 64);
            }
            if (lane == 0) {
                float mu = s * (1.f / 128.f);
                mu_s[r] = mu;
                rs_s[r] = rsqrtf(q * (1.f / 128.f) - mu * mu + EPSv);
            }
        }
        __syncthreads();
        for (int f = tid; f < TT * 64; f += 256) {
            int t = f >> 6, cp = f & 63;
            float mu = mu_s[t], rs = rs_s[t];
            float x0 = (As[t * 132 + 2 * cp]     - mu) * rs * g2[2 * cp]     + be2[2 * cp];
            float x1 = (As[t * 132 + 2 * cp + 1] - mu) * rs * g2[2 * cp + 1] + be2[2 * cp + 1];
            ((unsigned*)(Ab + t * 136))[cp] = packbf(x0, x1);
        }
        __syncthreads();

        // ---- ff1: Fs = relu(Ab @ W1^T + b1)   (K=128, N=512; wave: 8 tiles)
        {
            short8 a[4];
            const ushort* ar = Ab + ml * 136 + quad * 8;
#pragma unroll
            for (int ks = 0; ks < 4; ks++) a[ks] = *(const short8*)(ar + ks * 32);
#pragma unroll
            for (int i = 0; i < 8; i++) {
                int n0 = (wv * 8 + i) * 16;
                f32x4 acc = (f32x4){0.f, 0.f, 0.f, 0.f};
                const ushort* wb = W1B + (size_t)(l * 512 + n0 + ml) * 128 + quad * 8;
#pragma unroll
                for (int ks = 0; ks < 4; ks++) {
                    short8 bfr = *(const short8*)(wb + ks * 32);
                    acc = __builtin_amdgcn_mfma_f32_16x16x32_bf16(a[ks], bfr, acc, 0, 0, 0);
                }
                int col = n0 + ml;
                float bb = b1l[col];
#pragma unroll
                for (int r = 0; r < 4; r++) {
                    int row = quad * 4 + r;
                    if (row < TT) Fs[row * 520 + col] = f2bu(fmaxf(acc[r] + bb, 0.f));
                }
            }
        }
        __syncthreads();

        // ---- ff2 + residual: As += Fs @ W2^T + b2   (K=512, N=128; wave: 2 tiles)
        {
            f32x4 acc[2];
#pragma unroll
            for (int i = 0; i < 2; i++) acc[i] = (f32x4){0.f, 0.f, 0.f, 0.f};
            const ushort* ar = Fs + ml * 520 + quad * 8;
            for (int ks = 0; ks < 16; ks++) {
                short8 a = *(const short8*)(ar + ks * 32);
#pragma unroll
                for (int i = 0; i < 2; i++) {
                    int n0 = (wv * 2 + i) * 16;
                    short8 bfr = *(const short8*)(W2B + (size_t)(l * 128 + n0 + ml) * 512 + quad * 8 + ks * 32);
                    acc[i] = __builtin_amdgcn_mfma_f32_16x16x32_bf16(a, bfr, acc[i], 0, 0, 0);
                }
            }
#pragma unroll
            for (int i = 0; i < 2; i++) {
                int col = (wv * 2 + i) * 16 + ml;
                float bb = b2l[col];
#pragma unroll
                for (int r = 0; r < 4; r++) {
                    int row = quad * 4 + r;
                    if (row < TT) As[row * 132 + col] += acc[i][r] + bb;
                }
            }
        }
        __syncthreads();
    }

    // ---- tail: act_emb + mv_emb
    if (tid < 128) {
        float s = 0.f;
#pragma unroll
        for (int t = 0; t < TT; t++) s += As[t * 132 + tid];
        out[(size_t)b * 26 * Cc + 24 * Cc + tid] = s * (1.f / 15.f);
    } else if (tid < 256) {
        int co = tid - 128;
        float v = ss[b] * Wsc[co] + bsc[co];
        out[(size_t)b * 26 * Cc + 25 * Cc + co] = fmaxf(v, 0.f);
    }
}

// ---------------------------------------------------------------------------
extern "C" void kernel_launch(void* const* d_in, const int* in_sizes, int n_in,
                              void* d_out, int out_size, void* d_ws, size_t ws_size,
                              hipStream_t stream)
{
    (void)in_sizes; (void)n_in; (void)out_size; (void)ws_size;
    const int*   xx   = (const int*)d_in[0];
    const float* ss   = (const float*)d_in[1];
    const float* Win  = (const float*)d_in[2];
    const float* b_in = (const float*)d_in[3];
    const float* Wl   = (const float*)d_in[4];
    const float* bl   = (const float*)d_in[5];
    const float* Wr   = (const float*)d_in[6];
    const float* lng  = (const float*)d_in[7];
    const float* lnb  = (const float*)d_in[8];
    const float* Wqkv = (const float*)d_in[9];
    const float* bqkv = (const float*)d_in[10];
    const float* Wo   = (const float*)d_in[11];
    const float* bo   = (const float*)d_in[12];
    const float* ln1g = (const float*)d_in[13];
    const float* ln1b = (const float*)d_in[14];
    const float* ln2g = (const float*)d_in[15];
    const float* ln2b = (const float*)d_in[16];
    const float* W1   = (const float*)d_in[17];
    const float* b1   = (const float*)d_in[18];
    const float* W2   = (const float*)d_in[19];
    const float* b2   = (const float*)d_in[20];
    const float* Wact = (const float*)d_in[21];
    const float* bact = (const float*)d_in[22];
    const float* Wsc  = (const float*)d_in[23];
    const float* bsc  = (const float*)d_in[24];
    float* out = (float*)d_out;

    char* ws = (char*)d_ws;
    size_t off = 0;
    bf16*  xbuf = (bf16*)(ws + off);  off += (size_t)Bsz * S3 * Cc * 2;
    float* sA   = (float*)(ws + off); off += (size_t)Bsz * Cc * 4;
    float* sB   = (float*)(ws + off); off += (size_t)Bsz * Cc * 4;
    float* invb = (float*)(ws + off); off += (size_t)Bsz * 4;
    float* mbuf = (float*)(ws + off); off += (size_t)Bsz * S3 * 4;
    float* WlT  = (float*)(ws + off); off += 384 * 128 * 4;
    ushort* dbuf  = (ushort*)(ws + off); off += (size_t)Bsz * 16384 * 2;
    ushort* WactB = (ushort*)(ws + off); off += 128 * 512 * 2;
    ushort* WqkvB = (ushort*)(ws + off); off += 768 * 128 * 2;
    ushort* WoB   = (ushort*)(ws + off); off += 256 * 128 * 2;
    ushort* W1B   = (ushort*)(ws + off); off += 1024 * 128 * 2;
    ushort* W2B   = (ushort*)(ws + off); off += 256 * 512 * 2;

    // packed Wl (fp32, for k_gnn base) + bf16 weight conversions
    k_tpack<<<dim3(4, 12), 256, 0, stream>>>(Wl, WlT, 384, 128);
    k_cvt<<<(128 * 512 / 4 + 255) / 256, 256, 0, stream>>>(Wact, WactB, 128 * 512 / 4);
    k_cvt<<<(768 * 128 / 4 + 255) / 256, 256, 0, stream>>>(Wqkv, WqkvB, 768 * 128 / 4);
    k_cvt<<<(256 * 128 / 4 + 255) / 256, 256, 0, stream>>>(Wo,   WoB,   256 * 128 / 4);
    k_cvt<<<(1024 * 128 / 4 + 255) / 256, 256, 0, stream>>>(W1,  W1B,  1024 * 128 / 4);
    k_cvt<<<(256 * 512 / 4 + 255) / 256, 256, 0, stream>>>(W2,   W2B,   256 * 512 / 4);

    k_init<<<Bsz, 512, 0, stream>>>(xx, ss, Win, b_in, xbuf, sA, invb, mbuf);

    // GNN layers
    k_dw<<<Bsz, 256, 0, stream>>>(Wl, Wr, invb, dbuf);
    hipMemsetAsync(sB, 0, (size_t)Bsz * Cc * 4, stream);
    k_gnn<<<Bsz * 8, 256, 0, stream>>>(xbuf, sA, invb, dbuf,
                                       (const float4*)WlT, 0, bl,
                                       lng, lnb, mbuf, sB, 1);
    k_dw<<<Bsz, 256, 0, stream>>>(Wl + 16384, Wr + 16384, invb, dbuf);
    hipMemsetAsync(sA, 0, (size_t)Bsz * Cc * 4, stream);
    k_gnn<<<Bsz * 8, 256, 0, stream>>>(xbuf, sB, invb, dbuf,
                                       (const float4*)WlT, 128, bl + 128,
                                       lng, lnb, mbuf, sA, 1);
    k_dw<<<Bsz, 256, 0, stream>>>(Wl + 32768, Wr + 32768, invb, dbuf);
    k_gnn<<<Bsz * 8, 256, 0, stream>>>(xbuf, sA, invb, dbuf,
                                       (const float4*)WlT, 256, bl + 256,
                                       lng, lnb, mbuf, sB, 0);

    k_pool<<<Bsz, 256, 0, stream>>>(xbuf, mbuf, out);

    k_tf3<<<Bsz, 256, 0, stream>>>(xx, ss,
                                   WactB, bact, WqkvB, bqkv, WoB, bo,
                                   ln1g, ln1b, ln2g, ln2b,
                                   W1B, b1, W2B, b2,
                                   Wsc, bsc, out);
}

// Round 5
// 353.624 us; speedup vs baseline: 7.9052x; 1.6844x over previous
//
#include <hip/hip_runtime.h>
#include <hip/hip_bf16.h>
#include <string.h>

typedef __hip_bfloat16 bf16;
typedef __attribute__((ext_vector_type(8))) short short8;
typedef __attribute__((ext_vector_type(4))) float f32x4;

#define Bsz 512
#define S3  512
#define Tsz 16
#define Cc  128
#define TT  15
#define EPSv 1e-5f

__device__ __forceinline__ float u2f(unsigned short u) {
    return __uint_as_float(((unsigned)u) << 16);
}
__device__ __forceinline__ unsigned short f2bu(float v) {
    bf16 h = __float2bfloat16(v);
    unsigned short u; memcpy(&u, &h, 2); return u;
}
__device__ __forceinline__ unsigned packbf(float a, float b) {
    return (unsigned)f2bu(a) | ((unsigned)f2bu(b) << 16);
}
__device__ __forceinline__ float dot4(float4 a, float4 b) {
    return a.x*b.x + a.y*b.y + a.z*b.z + a.w*b.w;
}

// ---------------------------------------------------------------------------
// k_tpack: src (NR x NK) row-major fp32 -> float4-packed k-major (Wl for base)
// ---------------------------------------------------------------------------
__global__ __launch_bounds__(256) void k_tpack(const float* __restrict__ src,
                                               float* __restrict__ dst,
                                               int NR, int NK)
{
    __shared__ float tile[32][33];
    int k0 = blockIdx.x * 32, r0 = blockIdx.y * 32;
    int lr = threadIdx.x >> 5, lk = threadIdx.x & 31;
    for (int i = lr; i < 32; i += 8)
        tile[i][lk] = src[(size_t)(r0 + i) * NK + k0 + lk];
    __syncthreads();
    int c = threadIdx.x & 31, k4 = threadIdx.x >> 5;
    float4 v;
    v.x = tile[c][k4 * 4 + 0]; v.y = tile[c][k4 * 4 + 1];
    v.z = tile[c][k4 * 4 + 2]; v.w = tile[c][k4 * 4 + 3];
    ((float4*)dst)[(size_t)(k0 / 4 + k4) * NR + r0 + c] = v;
}

// ---------------------------------------------------------------------------
// k_cvt: fp32 -> bf16 elementwise
// ---------------------------------------------------------------------------
__global__ __launch_bounds__(256) void k_cvt(const float* __restrict__ src,
                                             ushort* __restrict__ dst, int n4)
{
    int i = blockIdx.x * 256 + threadIdx.x;
    if (i < n4) {
        float4 v = ((const float4*)src)[i];
        ushort4 o;
        o.x = f2bu(v.x); o.y = f2bu(v.y); o.z = f2bu(v.z); o.w = f2bu(v.w);
        ((ushort4*)dst)[i] = o;
    }
}

// ---------------------------------------------------------------------------
// k_dwall: d = Wr - inv*Wl -> bf16 in MFMA-fragment-major layout.
// grid (Bsz, 3); block 256. Computes inv from frame0 inline.
// Layout: dbuf[((b*3+l)*32 + (t*4+ks))*512 + lane*8 + j]
//   where t = n-tile(0..7), ks = k-step(0..3), lane=(ml|quad<<4),
//   n = t*16+ml, k = ks*32 + quad*8 + j  -> B-frag loads are lane-consecutive.
// ---------------------------------------------------------------------------
__global__ __launch_bounds__(256) void k_dwall(
    const int* __restrict__ xx, const float* __restrict__ Wl,
    const float* __restrict__ Wr, ushort* __restrict__ dbuf)
{
    __shared__ float pc[4];
    __shared__ float winv;
    int b = blockIdx.x, l = blockIdx.y, tid = threadIdx.x;
    const int* x0 = xx + (size_t)b * Tsz * S3;
    int c = (x0[tid] != 0) + (x0[tid + 256] != 0);
    for (int off = 32; off; off >>= 1) c += __shfl_xor(c, off, 64);
    if ((tid & 63) == 0) pc[tid >> 6] = (float)c;
    __syncthreads();
    if (tid == 0) {
        float n = pc[0] + pc[1] + pc[2] + pc[3];
        winv = (n > 1.f) ? 1.f / (n - 1.f) : 0.f;
    }
    __syncthreads();
    float inv = winv;
    const float* wl = Wl + l * 16384;
    const float* wr = Wr + l * 16384;
    ushort* dst = dbuf + (size_t)(b * 3 + l) * 32 * 512;
    for (int item = tid; item < 2048; item += 256) {
        int f = item >> 6, lane = item & 63;
        int t = f >> 2, ks = f & 3, ml = lane & 15, q = lane >> 4;
        int n = t * 16 + ml, kb = ks * 32 + q * 8;
        const float4* wlr = (const float4*)(wl + n * 128 + kb);
        const float4* wrr = (const float4*)(wr + n * 128 + kb);
        float4 a0 = wlr[0], a1 = wlr[1];
        float4 r0 = wrr[0], r1 = wrr[1];
        ushort4 o0, o1;
        o0.x = f2bu(r0.x - inv * a0.x); o0.y = f2bu(r0.y - inv * a0.y);
        o0.z = f2bu(r0.z - inv * a0.z); o0.w = f2bu(r0.w - inv * a0.w);
        o1.x = f2bu(r1.x - inv * a1.x); o1.y = f2bu(r1.y - inv * a1.y);
        o1.z = f2bu(r1.z - inv * a1.z); o1.w = f2bu(r1.w - inv * a1.w);
        ushort* dp = dst + (size_t)f * 512 + lane * 8;
        *(ushort4*)dp = o0;
        *(ushort4*)(dp + 4) = o1;
    }
}

// ---------------------------------------------------------------------------
// k_torso: fused init + 3 GNN layers + pool, whole batch resident in LDS.
// 512 threads (8 waves); wave wv owns nodes [wv*64, wv*64+64).
// ---------------------------------------------------------------------------
__global__ __launch_bounds__(512, 2) void k_torso(
    const int* __restrict__ xx, const float* __restrict__ ss,
    const float* __restrict__ Win, const float* __restrict__ b_in,
    const ushort* __restrict__ dbuf,
    const float4* __restrict__ WlP, const float* __restrict__ blv,
    const float* __restrict__ lng, const float* __restrict__ lnb,
    float* __restrict__ out)
{
    __shared__ ushort X[512 * 136];      // x (bf16), row stride 136
    __shared__ float  mC[512];           // mask
    __shared__ float  sred[8 * 128];
    __shared__ float  ssc[128];          // s * inv
    __shared__ float  sbase[128];        // bl + (s*inv) @ Wl^T
    __shared__ float  gln[128], bln[128];
    __shared__ float  scnt[8];
    __shared__ float  invS;

    int b = blockIdx.x, tid = threadIdx.x;
    int wv = tid >> 6, lane = tid & 63;
    int ml = lane & 15, quad = lane >> 4;

    // ================= init: lin_in into LDS, mask, s0, inv =================
    {
        int g = wv, cp = lane;
        int co0 = 2 * cp, co1 = 2 * cp + 1;
        const int* x0 = xx + (size_t)b * Tsz * S3;
        float f4c = ss[b] * (1.0f / 8.0f);
        float a0 = Win[co0*5+0], a1 = Win[co0*5+1], a2 = Win[co0*5+2], a3 = Win[co0*5+3], a4 = Win[co0*5+4];
        float c0 = Win[co1*5+0], c1 = Win[co1*5+1], c2 = Win[co1*5+2], c3 = Win[co1*5+3], c4 = Win[co1*5+4];
        float ba = b_in[co0], bc = b_in[co1];
        float sp0 = 0.f, sp1 = 0.f; int cnt = 0;
        for (int node = g; node < S3; node += 8) {
            int f0 = x0[node];
            float m = (f0 != 0) ? 1.f : 0.f;
            float ci = (float)(node >> 6) * (1.f / 7.f);
            float cj = (float)((node >> 3) & 7) * (1.f / 7.f);
            float ck = (float)(node & 7) * (1.f / 7.f);
            float ft = (float)f0 * 0.5f;
            float v0 = ba + ci * a0 + cj * a1 + ck * a2 + ft * a3 + f4c * a4;
            float v1 = bc + ci * c0 + cj * c1 + ck * c2 + ft * c3 + f4c * c4;
            ((unsigned*)(X + node * 136))[cp] = packbf(v0, v1);
            sp0 += v0 * m; sp1 += v1 * m;
            cnt += (f0 != 0);
            if (cp == 0) mC[node] = m;
        }
        sred[g * 128 + co0] = sp0;
        sred[g * 128 + co1] = sp1;
        if (cp == 0) scnt[g] = (float)cnt;
    }
    if (tid < 128) { gln[tid] = lng[tid]; bln[tid] = lnb[tid]; }
    __syncthreads();
    if (tid == 0) {
        float n = 0.f;
#pragma unroll
        for (int g = 0; g < 8; g++) n += scnt[g];
        invS = (n > 1.f) ? 1.f / (n - 1.f) : 0.f;
    }
    __syncthreads();
    if (tid < 128) {
        float s = 0.f;
#pragma unroll
        for (int g = 0; g < 8; g++) s += sred[g * 128 + tid];
        ssc[tid] = s * invS;
    }
    __syncthreads();
    if (tid < 128) {
        float a = blv[tid];
        for (int k4 = 0; k4 < 32; k4++)
            a += dot4(*(const float4*)(ssc + k4 * 4), WlP[k4 * 384 + tid]);
        sbase[tid] = a;
    }
    __syncthreads();

    // ================= 3 SAGE layers =================
    for (int l = 0; l < 3; l++) {
        f32x4 acc[4][8];
#pragma unroll
        for (int m = 0; m < 4; m++)
#pragma unroll
            for (int t = 0; t < 8; t++) acc[m][t] = (f32x4){0.f, 0.f, 0.f, 0.f};

        const ushort* dL = dbuf + (size_t)(b * 3 + l) * 32 * 512;
#pragma unroll
        for (int ks = 0; ks < 4; ks++) {
            short8 bfr[8];
#pragma unroll
            for (int t = 0; t < 8; t++)
                bfr[t] = *(const short8*)(dL + (size_t)(t * 4 + ks) * 512 + lane * 8);
#pragma unroll
            for (int m = 0; m < 4; m++) {
                short8 a = *(const short8*)(X + (wv * 64 + m * 16 + ml) * 136 + quad * 8 + ks * 32);
#pragma unroll
                for (int t = 0; t < 8; t++)
                    acc[m][t] = __builtin_amdgcn_mfma_f32_16x16x32_bf16(a, bfr[t], acc[m][t], 0, 0, 0);
            }
        }

        // epilogue: relu+base -> LN (shuffle stats) -> bf16 back into X
        float bse[8], gg[8], be[8];
#pragma unroll
        for (int t = 0; t < 8; t++) {
            bse[t] = sbase[t * 16 + ml];
            gg[t]  = gln[t * 16 + ml];
            be[t]  = bln[t * 16 + ml];
        }
        float sp[8];
#pragma unroll
        for (int t = 0; t < 8; t++) sp[t] = 0.f;
        bool last = (l == 2);

#pragma unroll
        for (int m = 0; m < 4; m++) {
#pragma unroll
            for (int r = 0; r < 4; r++) {
                int row = wv * 64 + m * 16 + quad * 4 + r;
                float h[8];
                float s = 0.f, q = 0.f;
#pragma unroll
                for (int t = 0; t < 8; t++) {
                    float v = fmaxf(acc[m][t][r] + bse[t], 0.f);
                    h[t] = v; s += v; q += v * v;
                }
#pragma unroll
                for (int off = 1; off <= 8; off <<= 1) {
                    s += __shfl_xor(s, off, 64);
                    q += __shfl_xor(q, off, 64);
                }
                float mu = s * (1.f / 128.f);
                float rs = rsqrtf(q * (1.f / 128.f) - mu * mu + EPSv);
                float mrow = mC[row];
#pragma unroll
                for (int t = 0; t < 8; t++) {
                    float y = (h[t] - mu) * rs * gg[t] + be[t];
                    if (last) y *= mrow;   // final x only feeds pool (masked)
                    else sp[t] += y * mrow;
                    X[row * 136 + t * 16 + ml] = f2bu(y);
                }
            }
        }

        if (!last) {
            // reduce masked sum across quads, then waves; next-layer base
#pragma unroll
            for (int t = 0; t < 8; t++) {
                sp[t] += __shfl_xor(sp[t], 16, 64);
                sp[t] += __shfl_xor(sp[t], 32, 64);
            }
            if (quad == 0) {
#pragma unroll
                for (int t = 0; t < 8; t++) sred[wv * 128 + t * 16 + ml] = sp[t];
            }
            __syncthreads();
            if (tid < 128) {
                float s = 0.f;
#pragma unroll
                for (int g = 0; g < 8; g++) s += sred[g * 128 + tid];
                ssc[tid] = s * invS;
            }
            __syncthreads();
            if (tid < 128) {
                float a = blv[(l + 1) * 128 + tid];
                for (int k4 = 0; k4 < 32; k4++)
                    a += dot4(*(const float4*)(ssc + k4 * 4), WlP[k4 * 384 + (l + 1) * 128 + tid]);
                sbase[tid] = a;
            }
            __syncthreads();
        }
    }
    __syncthreads();

    // ================= pool: slice means (x already masked) =================
    for (int f = tid; f < 24 * 128; f += 512) {
        int p = f >> 7, c = f & 127;
        int axis = p >> 3, idx = p & 7;
        float sum = 0.f;
        for (int t = 0; t < 64; t++) {
            int node;
            if (axis == 0)      node = idx * 64 + t;
            else if (axis == 1) node = (t >> 3) * 64 + idx * 8 + (t & 7);
            else                node = t * 8 + idx;
            sum += u2f(X[node * 136 + c]);
        }
        out[(size_t)b * 26 * Cc + p * Cc + c] = sum * (1.f / 64.f);
    }
}

// ---------------------------------------------------------------------------
// k_tf3: transformer with bf16 MFMA GEMMs (unchanged from round 4)
// ---------------------------------------------------------------------------
__global__ __launch_bounds__(256) void k_tf3(
    const int* __restrict__ xx, const float* __restrict__ ss,
    const ushort* __restrict__ WactB, const float* __restrict__ bact,
    const ushort* __restrict__ WqkvB, const float* __restrict__ bqkv,
    const ushort* __restrict__ WoB, const float* __restrict__ bo,
    const float* __restrict__ ln1g, const float* __restrict__ ln1b,
    const float* __restrict__ ln2g, const float* __restrict__ ln2b,
    const ushort* __restrict__ W1B, const float* __restrict__ b1v,
    const ushort* __restrict__ W2B, const float* __restrict__ b2v,
    const float* __restrict__ Wsc, const float* __restrict__ bsc,
    float* __restrict__ out)
{
    __shared__ float  As[TT * 132];
    __shared__ float  Qs[TT * 388];
    __shared__ ushort Ab[16 * 136];
    __shared__ ushort Hs[16 * 136];
    __shared__ ushort Fs[16 * 520];
    __shared__ float  Att[60 * 16];
    __shared__ float  mu_s[TT], rs_s[TT];

    int b = blockIdx.x, tid = threadIdx.x;
    int wv = tid >> 6, lane = tid & 63;
    int ml = lane & 15, quad = lane >> 4;

    const int* xa = xx + (size_t)b * Tsz * S3 + S3;
    for (int f = tid; f < TT * 512; f += 256) {
        int t = f >> 9, s = f & 511;
        Fs[t * 520 + s] = f2bu((float)xa[t * 512 + s]);
    }
    __syncthreads();

    {
        f32x4 acc[2];
#pragma unroll
        for (int i = 0; i < 2; i++) acc[i] = (f32x4){0.f, 0.f, 0.f, 0.f};
        const ushort* ar = Fs + ml * 520 + quad * 8;
        for (int ks = 0; ks < 16; ks++) {
            short8 a = *(const short8*)(ar + ks * 32);
#pragma unroll
            for (int i = 0; i < 2; i++) {
                int n0 = (wv * 2 + i) * 16;
                short8 bfr = *(const short8*)(WactB + (size_t)(n0 + ml) * 512 + quad * 8 + ks * 32);
                acc[i] = __builtin_amdgcn_mfma_f32_16x16x32_bf16(a, bfr, acc[i], 0, 0, 0);
            }
        }
#pragma unroll
        for (int i = 0; i < 2; i++) {
            int col = (wv * 2 + i) * 16 + ml;
            float bb = bact[col];
#pragma unroll
            for (int r = 0; r < 4; r++) {
                int row = quad * 4 + r;
                if (row < TT) As[row * 132 + col] = acc[i][r] + bb;
            }
        }
    }
    __syncthreads();

    for (int l = 0; l < 2; l++) {
        const float* bq  = bqkv + l * 384;
        const float* bol = bo + l * 128;
        const float* g1  = ln1g + l * 128; const float* be1 = ln1b + l * 128;
        const float* g2  = ln2g + l * 128; const float* be2 = ln2b + l * 128;
        const float* b1l = b1v + l * 512;  const float* b2l = b2v + l * 128;

        for (int r = wv; r < TT; r += 4) {
            float2 v = *(const float2*)(As + r * 132 + lane * 2);
            float s = v.x + v.y, q = v.x * v.x + v.y * v.y;
            for (int off = 32; off; off >>= 1) {
                s += __shfl_xor(s, off, 64);
                q += __shfl_xor(q, off, 64);
            }
            if (lane == 0) {
                float mu = s * (1.f / 128.f);
                mu_s[r] = mu;
                rs_s[r] = rsqrtf(q * (1.f / 128.f) - mu * mu + EPSv);
            }
        }
        __syncthreads();
        for (int f = tid; f < TT * 64; f += 256) {
            int t = f >> 6, cp = f & 63;
            float mu = mu_s[t], rs = rs_s[t];
            float x0 = (As[t * 132 + 2 * cp]     - mu) * rs * g1[2 * cp]     + be1[2 * cp];
            float x1 = (As[t * 132 + 2 * cp + 1] - mu) * rs * g1[2 * cp + 1] + be1[2 * cp + 1];
            ((unsigned*)(Ab + t * 136))[cp] = packbf(x0, x1);
        }
        __syncthreads();

        {
            short8 a[4];
            const ushort* ar = Ab + ml * 136 + quad * 8;
#pragma unroll
            for (int ks = 0; ks < 4; ks++) a[ks] = *(const short8*)(ar + ks * 32);
#pragma unroll
            for (int i = 0; i < 6; i++) {
                int n0 = (wv * 6 + i) * 16;
                f32x4 acc = (f32x4){0.f, 0.f, 0.f, 0.f};
                const ushort* wb = WqkvB + (size_t)(l * 384 + n0 + ml) * 128 + quad * 8;
#pragma unroll
                for (int ks = 0; ks < 4; ks++) {
                    short8 bfr = *(const short8*)(wb + ks * 32);
                    acc = __builtin_amdgcn_mfma_f32_16x16x32_bf16(a[ks], bfr, acc, 0, 0, 0);
                }
                int col = n0 + ml;
                float bb = bq[col];
#pragma unroll
                for (int r = 0; r < 4; r++) {
                    int row = quad * 4 + r;
                    if (row < TT) Qs[row * 388 + col] = acc[r] + bb;
                }
            }
        }
        __syncthreads();

        if (tid < 60) {
            int h = tid / 15, tq = tid % 15;
            const float* qp = Qs + tq * 388 + h * 32;
            float sc[TT];
            float mx = -1e30f;
#pragma unroll
            for (int tk = 0; tk < TT; tk++) {
                const float* kp = Qs + tk * 388 + 128 + h * 32;
                float d = 0.f;
#pragma unroll
                for (int u = 0; u < 32; u += 4)
                    d += dot4(*(const float4*)(qp + u), *(const float4*)(kp + u));
                d *= 0.17677669529663689f;
                sc[tk] = d; mx = fmaxf(mx, d);
            }
            float sum = 0.f;
#pragma unroll
            for (int tk = 0; tk < TT; tk++) { float e = __expf(sc[tk] - mx); sc[tk] = e; sum += e; }
            float r = 1.f / sum;
#pragma unroll
            for (int tk = 0; tk < TT; tk++) Att[tid * 16 + tk] = sc[tk] * r;
        }
        __syncthreads();

        for (int f = tid; f < TT * 64; f += 256) {
            int t = f >> 6, cp = f & 63;
            int c0 = 2 * cp, c1 = 2 * cp + 1;
            int h = c0 >> 5;
            const float* ap = Att + (h * 15 + t) * 16;
            const float* vp = Qs + 256;
            float a0 = 0.f, a1 = 0.f;
#pragma unroll
            for (int tk = 0; tk < TT; tk++) {
                float w = ap[tk];
                a0 += w * vp[tk * 388 + c0];
                a1 += w * vp[tk * 388 + c1];
            }
            ((unsigned*)(Hs + t * 136))[cp] = packbf(a0, a1);
        }
        __syncthreads();

        {
            short8 a[4];
            const ushort* ar = Hs + ml * 136 + quad * 8;
#pragma unroll
            for (int ks = 0; ks < 4; ks++) a[ks] = *(const short8*)(ar + ks * 32);
#pragma unroll
            for (int i = 0; i < 2; i++) {
                int n0 = (wv * 2 + i) * 16;
                f32x4 acc = (f32x4){0.f, 0.f, 0.f, 0.f};
                const ushort* wb = WoB + (size_t)(l * 128 + n0 + ml) * 128 + quad * 8;
#pragma unroll
                for (int ks = 0; ks < 4; ks++) {
                    short8 bfr = *(const short8*)(wb + ks * 32);
                    acc = __builtin_amdgcn_mfma_f32_16x16x32_bf16(a[ks], bfr, acc, 0, 0, 0);
                }
                int col = n0 + ml;
                float bb = bol[col];
#pragma unroll
                for (int r = 0; r < 4; r++) {
                    int row = quad * 4 + r;
                    if (row < TT) As[row * 132 + col] += acc[r] + bb;
                }
            }
        }
        __syncthreads();

        for (int r = wv; r < TT; r += 4) {
            float2 v = *(const float2*)(As + r * 132 + lane * 2);
            float s = v.x + v.y, q = v.x * v.x + v.y * v.y;
            for (int off = 32; off; off >>= 1) {
                s += __shfl_xor(s, off, 64);
                q += __shfl_xor(q, off, 64);
            }
            if (lane == 0) {
                float mu = s * (1.f / 128.f);
                mu_s[r] = mu;
                rs_s[r] = rsqrtf(q * (1.f / 128.f) - mu * mu + EPSv);
            }
        }
        __syncthreads();
        for (int f = tid; f < TT * 64; f += 256) {
            int t = f >> 6, cp = f & 63;
            float mu = mu_s[t], rs = rs_s[t];
            float x0 = (As[t * 132 + 2 * cp]     - mu) * rs * g2[2 * cp]     + be2[2 * cp];
            float x1 = (As[t * 132 + 2 * cp + 1] - mu) * rs * g2[2 * cp + 1] + be2[2 * cp + 1];
            ((unsigned*)(Ab + t * 136))[cp] = packbf(x0, x1);
        }
        __syncthreads();

        {
            short8 a[4];
            const ushort* ar = Ab + ml * 136 + quad * 8;
#pragma unroll
            for (int ks = 0; ks < 4; ks++) a[ks] = *(const short8*)(ar + ks * 32);
#pragma unroll
            for (int i = 0; i < 8; i++) {
                int n0 = (wv * 8 + i) * 16;
                f32x4 acc = (f32x4){0.f, 0.f, 0.f, 0.f};
                const ushort* wb = W1B + (size_t)(l * 512 + n0 + ml) * 128 + quad * 8;
#pragma unroll
                for (int ks = 0; ks < 4; ks++) {
                    short8 bfr = *(const short8*)(wb + ks * 32);
                    acc = __builtin_amdgcn_mfma_f32_16x16x32_bf16(a[ks], bfr, acc, 0, 0, 0);
                }
                int col = n0 + ml;
                float bb = b1l[col];
#pragma unroll
                for (int r = 0; r < 4; r++) {
                    int row = quad * 4 + r;
                    if (row < TT) Fs[row * 520 + col] = f2bu(fmaxf(acc[r] + bb, 0.f));
                }
            }
        }
        __syncthreads();

        {
            f32x4 acc[2];
#pragma unroll
            for (int i = 0; i < 2; i++) acc[i] = (f32x4){0.f, 0.f, 0.f, 0.f};
            const ushort* ar = Fs + ml * 520 + quad * 8;
            for (int ks = 0; ks < 16; ks++) {
                short8 a = *(const short8*)(ar + ks * 32);
#pragma unroll
                for (int i = 0; i < 2; i++) {
                    int n0 = (wv * 2 + i) * 16;
                    short8 bfr = *(const short8*)(W2B + (size_t)(l * 128 + n0 + ml) * 512 + quad * 8 + ks * 32);
                    acc[i] = __builtin_amdgcn_mfma_f32_16x16x32_bf16(a, bfr, acc[i], 0, 0, 0);
                }
            }
#pragma unroll
            for (int i = 0; i < 2; i++) {
                int col = (wv * 2 + i) * 16 + ml;
                float bb = b2l[col];
#pragma unroll
                for (int r = 0; r < 4; r++) {
                    int row = quad * 4 + r;
                    if (row < TT) As[row * 132 + col] += acc[i][r] + bb;
                }
            }
        }
        __syncthreads();
    }

    if (tid < 128) {
        float s = 0.f;
#pragma unroll
        for (int t = 0; t < TT; t++) s += As[t * 132 + tid];
        out[(size_t)b * 26 * Cc + 24 * Cc + tid] = s * (1.f / 15.f);
    } else if (tid < 256) {
        int co = tid - 128;
        float v = ss[b] * Wsc[co] + bsc[co];
        out[(size_t)b * 26 * Cc + 25 * Cc + co] = fmaxf(v, 0.f);
    }
}

// ---------------------------------------------------------------------------
extern "C" void kernel_launch(void* const* d_in, const int* in_sizes, int n_in,
                              void* d_out, int out_size, void* d_ws, size_t ws_size,
                              hipStream_t stream)
{
    (void)in_sizes; (void)n_in; (void)out_size; (void)ws_size;
    const int*   xx   = (const int*)d_in[0];
    const float* ss   = (const float*)d_in[1];
    const float* Win  = (const float*)d_in[2];
    const float* b_in = (const float*)d_in[3];
    const float* Wl   = (const float*)d_in[4];
    const float* bl   = (const float*)d_in[5];
    const float* Wr   = (const float*)d_in[6];
    const float* lng  = (const float*)d_in[7];
    const float* lnb  = (const float*)d_in[8];
    const float* Wqkv = (const float*)d_in[9];
    const float* bqkv = (const float*)d_in[10];
    const float* Wo   = (const float*)d_in[11];
    const float* bo   = (const float*)d_in[12];
    const float* ln1g = (const float*)d_in[13];
    const float* ln1b = (const float*)d_in[14];
    const float* ln2g = (const float*)d_in[15];
    const float* ln2b = (const float*)d_in[16];
    const float* W1   = (const float*)d_in[17];
    const float* b1   = (const float*)d_in[18];
    const float* W2   = (const float*)d_in[19];
    const float* b2   = (const float*)d_in[20];
    const float* Wact = (const float*)d_in[21];
    const float* bact = (const float*)d_in[22];
    const float* Wsc  = (const float*)d_in[23];
    const float* bsc  = (const float*)d_in[24];
    float* out = (float*)d_out;

    char* ws = (char*)d_ws;
    size_t off = 0;
    float* WlT  = (float*)(ws + off); off += 384 * 128 * 4;
    ushort* dbuf  = (ushort*)(ws + off); off += (size_t)Bsz * 3 * 32 * 512 * 2;  // 50.3 MB
    ushort* WactB = (ushort*)(ws + off); off += 128 * 512 * 2;
    ushort* WqkvB = (ushort*)(ws + off); off += 768 * 128 * 2;
    ushort* WoB   = (ushort*)(ws + off); off += 256 * 128 * 2;
    ushort* W1B   = (ushort*)(ws + off); off += 1024 * 128 * 2;
    ushort* W2B   = (ushort*)(ws + off); off += 256 * 512 * 2;

    k_tpack<<<dim3(4, 12), 256, 0, stream>>>(Wl, WlT, 384, 128);
    k_cvt<<<(128 * 512 / 4 + 255) / 256, 256, 0, stream>>>(Wact, WactB, 128 * 512 / 4);
    k_cvt<<<(768 * 128 / 4 + 255) / 256, 256, 0, stream>>>(Wqkv, WqkvB, 768 * 128 / 4);
    k_cvt<<<(256 * 128 / 4 + 255) / 256, 256, 0, stream>>>(Wo,   WoB,   256 * 128 / 4);
    k_cvt<<<(1024 * 128 / 4 + 255) / 256, 256, 0, stream>>>(W1,  W1B,  1024 * 128 / 4);
    k_cvt<<<(256 * 512 / 4 + 255) / 256, 256, 0, stream>>>(W2,   W2B,   256 * 512 / 4);

    k_dwall<<<dim3(Bsz, 3), 256, 0, stream>>>(xx, Wl, Wr, dbuf);

    k_torso<<<Bsz, 512, 0, stream>>>(xx, ss, Win, b_in, dbuf,
                                     (const float4*)WlT, bl, lng, lnb, out);

    k_tf3<<<Bsz, 256, 0, stream>>>(xx, ss,
                                   WactB, bact, WqkvB, bqkv, WoB, bo,
                                   ln1g, ln1b, ln2g, ln2b,
                                   W1B, b1, W2B, b2,
                                   Wsc, bsc, out);
}

// Round 6
// 332.982 us; speedup vs baseline: 8.3953x; 1.0620x over previous
//
#include <hip/hip_runtime.h>
#include <hip/hip_bf16.h>
#include <string.h>

typedef __hip_bfloat16 bf16;
typedef __attribute__((ext_vector_type(8))) short short8;
typedef __attribute__((ext_vector_type(4))) float f32x4;

#define Bsz 512
#define S3  512
#define Tsz 16
#define Cc  128
#define TT  15
#define EPSv 1e-5f

__device__ __forceinline__ float u2f(unsigned short u) {
    return __uint_as_float(((unsigned)u) << 16);
}
__device__ __forceinline__ unsigned short f2bu(float v) {
    bf16 h = __float2bfloat16(v);
    unsigned short u; memcpy(&u, &h, 2); return u;
}
__device__ __forceinline__ unsigned packbf(float a, float b) {
    return (unsigned)f2bu(a) | ((unsigned)f2bu(b) << 16);
}
// fast RNE bf16 (no NaN path — inputs finite)
__device__ __forceinline__ unsigned short bfr16(float a) {
    unsigned u = __float_as_uint(a);
    u = u + 0x7fffu + ((u >> 16) & 1u);
    return (unsigned short)(u >> 16);
}
__device__ __forceinline__ unsigned fpack2(float a, float b) {
    unsigned ua = __float_as_uint(a), ub = __float_as_uint(b);
    ua = ua + 0x7fffu + ((ua >> 16) & 1u);
    ub = ub + 0x7fffu + ((ub >> 16) & 1u);
    return (ua >> 16) | (ub & 0xffff0000u);
}
__device__ __forceinline__ float dot4(float4 a, float4 b) {
    return a.x*b.x + a.y*b.y + a.z*b.z + a.w*b.w;
}

// ---------------------------------------------------------------------------
// k_tpack: src (NR x NK) row-major fp32 -> float4-packed k-major (Wl for base)
// ---------------------------------------------------------------------------
__global__ __launch_bounds__(256) void k_tpack(const float* __restrict__ src,
                                               float* __restrict__ dst,
                                               int NR, int NK)
{
    __shared__ float tile[32][33];
    int k0 = blockIdx.x * 32, r0 = blockIdx.y * 32;
    int lr = threadIdx.x >> 5, lk = threadIdx.x & 31;
    for (int i = lr; i < 32; i += 8)
        tile[i][lk] = src[(size_t)(r0 + i) * NK + k0 + lk];
    __syncthreads();
    int c = threadIdx.x & 31, k4 = threadIdx.x >> 5;
    float4 v;
    v.x = tile[c][k4 * 4 + 0]; v.y = tile[c][k4 * 4 + 1];
    v.z = tile[c][k4 * 4 + 2]; v.w = tile[c][k4 * 4 + 3];
    ((float4*)dst)[(size_t)(k0 / 4 + k4) * NR + r0 + c] = v;
}

// ---------------------------------------------------------------------------
// k_cvt: fp32 -> bf16 elementwise
// ---------------------------------------------------------------------------
__global__ __launch_bounds__(256) void k_cvt(const float* __restrict__ src,
                                             ushort* __restrict__ dst, int n4)
{
    int i = blockIdx.x * 256 + threadIdx.x;
    if (i < n4) {
        float4 v = ((const float4*)src)[i];
        ushort4 o;
        o.x = f2bu(v.x); o.y = f2bu(v.y); o.z = f2bu(v.z); o.w = f2bu(v.w);
        ((ushort4*)dst)[i] = o;
    }
}

// ---------------------------------------------------------------------------
// k_dwall: d = Wr - inv*Wl -> bf16 in MFMA-fragment-major layout.
// grid (Bsz, 3); block 256. Computes inv from frame0 inline.
// dbuf[((b*3+l)*32 + (t*4+ks))*512 + lane*8 + j]
// ---------------------------------------------------------------------------
__global__ __launch_bounds__(256) void k_dwall(
    const int* __restrict__ xx, const float* __restrict__ Wl,
    const float* __restrict__ Wr, ushort* __restrict__ dbuf)
{
    __shared__ float pc[4];
    __shared__ float winv;
    int b = blockIdx.x, l = blockIdx.y, tid = threadIdx.x;
    const int* x0 = xx + (size_t)b * Tsz * S3;
    int c = (x0[tid] != 0) + (x0[tid + 256] != 0);
    for (int off = 32; off; off >>= 1) c += __shfl_xor(c, off, 64);
    if ((tid & 63) == 0) pc[tid >> 6] = (float)c;
    __syncthreads();
    if (tid == 0) {
        float n = pc[0] + pc[1] + pc[2] + pc[3];
        winv = (n > 1.f) ? 1.f / (n - 1.f) : 0.f;
    }
    __syncthreads();
    float inv = winv;
    const float* wl = Wl + l * 16384;
    const float* wr = Wr + l * 16384;
    ushort* dst = dbuf + (size_t)(b * 3 + l) * 32 * 512;
    for (int item = tid; item < 2048; item += 256) {
        int f = item >> 6, lane = item & 63;
        int t = f >> 2, ks = f & 3, ml = lane & 15, q = lane >> 4;
        int n = t * 16 + ml, kb = ks * 32 + q * 8;
        const float4* wlr = (const float4*)(wl + n * 128 + kb);
        const float4* wrr = (const float4*)(wr + n * 128 + kb);
        float4 a0 = wlr[0], a1 = wlr[1];
        float4 r0 = wrr[0], r1 = wrr[1];
        ushort4 o0, o1;
        o0.x = f2bu(r0.x - inv * a0.x); o0.y = f2bu(r0.y - inv * a0.y);
        o0.z = f2bu(r0.z - inv * a0.z); o0.w = f2bu(r0.w - inv * a0.w);
        o1.x = f2bu(r1.x - inv * a1.x); o1.y = f2bu(r1.y - inv * a1.y);
        o1.z = f2bu(r1.z - inv * a1.z); o1.w = f2bu(r1.w - inv * a1.w);
        ushort* dp = dst + (size_t)f * 512 + lane * 8;
        *(ushort4*)dp = o0;
        *(ushort4*)(dp + 4) = o1;
    }
}

// ---------------------------------------------------------------------------
// k_torso: fused init + 3 GNN layers + pool. 1024 threads (16 waves);
// wave wv owns nodes [wv*32, wv*32+32) -> acc[2][8] = 64 VGPRs.
// ---------------------------------------------------------------------------
__global__ __launch_bounds__(1024) void k_torso(
    const int* __restrict__ xx, const float* __restrict__ ss,
    const float* __restrict__ Win, const float* __restrict__ b_in,
    const ushort* __restrict__ dbuf,
    const float4* __restrict__ WlP, const float* __restrict__ blv,
    const float* __restrict__ lng, const float* __restrict__ lnb,
    float* __restrict__ out)
{
    __shared__ ushort X[512 * 136];      // 139264 B
    __shared__ float  mC[512];
    __shared__ float  sred[16 * 128];    // 8 KB
    __shared__ float  ssc[128];
    __shared__ float  sbase[128];
    __shared__ float  gln[128], bln[128];
    __shared__ float  scnt[16];
    __shared__ float  invS;

    int b = blockIdx.x, tid = threadIdx.x;
    int wv = tid >> 6, lane = tid & 63;
    int ml = lane & 15, quad = lane >> 4;

    // ================= init: lin_in into LDS, mask, s0, inv =================
    {
        int g = wv, cp = lane;             // g = wave = node phase, cp = channel pair
        int co0 = 2 * cp, co1 = 2 * cp + 1;
        const int* x0 = xx + (size_t)b * Tsz * S3;
        float f4c = ss[b] * (1.0f / 8.0f);
        float a0 = Win[co0*5+0], a1 = Win[co0*5+1], a2 = Win[co0*5+2], a3 = Win[co0*5+3];
        float c0 = Win[co1*5+0], c1 = Win[co1*5+1], c2 = Win[co1*5+2], c3 = Win[co1*5+3];
        float ba = b_in[co0] + f4c * Win[co0*5+4];
        float bc = b_in[co1] + f4c * Win[co1*5+4];
        float sp0 = 0.f, sp1 = 0.f; int cnt = 0;
        for (int node = g; node < S3; node += 16) {
            int f0 = x0[node];
            float m = (f0 != 0) ? 1.f : 0.f;
            float ci = (float)(node >> 6) * (1.f / 7.f);
            float cj = (float)((node >> 3) & 7) * (1.f / 7.f);
            float ck = (float)(node & 7) * (1.f / 7.f);
            float ft = (float)f0 * 0.5f;
            float v0 = ba + ci * a0 + cj * a1 + ck * a2 + ft * a3;
            float v1 = bc + ci * c0 + cj * c1 + ck * c2 + ft * c3;
            ((unsigned*)(X + node * 136))[cp] = fpack2(v0, v1);
            sp0 += v0 * m; sp1 += v1 * m;
            cnt += (f0 != 0);
            if (cp == 0) mC[node] = m;
        }
        sred[g * 128 + co0] = sp0;
        sred[g * 128 + co1] = sp1;
        if (cp == 0) scnt[g] = (float)cnt;
    }
    if (tid < 128) { gln[tid] = lng[tid]; bln[tid] = lnb[tid]; }
    __syncthreads();
    if (tid == 0) {
        float n = 0.f;
#pragma unroll
        for (int g = 0; g < 16; g++) n += scnt[g];
        invS = (n > 1.f) ? 1.f / (n - 1.f) : 0.f;
    }
    __syncthreads();
    if (tid < 128) {
        float s = 0.f;
#pragma unroll
        for (int g = 0; g < 16; g++) s += sred[g * 128 + tid];
        ssc[tid] = s * invS;
    }
    __syncthreads();
    if (tid < 128) {
        float a = blv[tid];
        for (int k4 = 0; k4 < 32; k4++)
            a += dot4(*(const float4*)(ssc + k4 * 4), WlP[k4 * 384 + tid]);
        sbase[tid] = a;
    }
    __syncthreads();

    // ================= 3 SAGE layers =================
    for (int l = 0; l < 3; l++) {
        f32x4 acc[2][8];
#pragma unroll
        for (int m = 0; m < 2; m++)
#pragma unroll
            for (int t = 0; t < 8; t++) acc[m][t] = (f32x4){0.f, 0.f, 0.f, 0.f};

        const ushort* dL = dbuf + (size_t)(b * 3 + l) * 32 * 512;
#pragma unroll
        for (int ks = 0; ks < 4; ks++) {
            short8 bfr[8];
#pragma unroll
            for (int t = 0; t < 8; t++)
                bfr[t] = *(const short8*)(dL + (size_t)(t * 4 + ks) * 512 + lane * 8);
#pragma unroll
            for (int m = 0; m < 2; m++) {
                short8 a = *(const short8*)(X + (wv * 32 + m * 16 + ml) * 136 + quad * 8 + ks * 32);
#pragma unroll
                for (int t = 0; t < 8; t++)
                    acc[m][t] = __builtin_amdgcn_mfma_f32_16x16x32_bf16(a, bfr[t], acc[m][t], 0, 0, 0);
            }
        }

        // epilogue: relu+base -> LN (shuffle stats over ml lanes) -> bf16 into X
        float bse[8], gg[8], be[8];
#pragma unroll
        for (int t = 0; t < 8; t++) {
            bse[t] = sbase[t * 16 + ml];
            gg[t]  = gln[t * 16 + ml];
            be[t]  = bln[t * 16 + ml];
        }
        float sp[8];
#pragma unroll
        for (int t = 0; t < 8; t++) sp[t] = 0.f;
        bool last = (l == 2);

#pragma unroll
        for (int m = 0; m < 2; m++) {
#pragma unroll
            for (int r = 0; r < 4; r++) {
                int row = wv * 32 + m * 16 + quad * 4 + r;
                float h[8];
                float s = 0.f, q = 0.f;
#pragma unroll
                for (int t = 0; t < 8; t++) {
                    float v = fmaxf(acc[m][t][r] + bse[t], 0.f);
                    h[t] = v; s += v; q += v * v;
                }
#pragma unroll
                for (int off = 1; off <= 8; off <<= 1) {
                    s += __shfl_xor(s, off, 64);
                    q += __shfl_xor(q, off, 64);
                }
                float mu = s * (1.f / 128.f);
                float rs = rsqrtf(q * (1.f / 128.f) - mu * mu + EPSv);
                float mrow = mC[row];
#pragma unroll
                for (int t = 0; t < 8; t++) {
                    float y = (h[t] - mu) * rs * gg[t] + be[t];
                    if (last) y *= mrow;
                    else sp[t] += y * mrow;
                    X[row * 136 + t * 16 + ml] = bfr16(y);
                }
            }
        }

        if (!last) {
#pragma unroll
            for (int t = 0; t < 8; t++) {
                sp[t] += __shfl_xor(sp[t], 16, 64);
                sp[t] += __shfl_xor(sp[t], 32, 64);
            }
            if (quad == 0) {
#pragma unroll
                for (int t = 0; t < 8; t++) sred[wv * 128 + t * 16 + ml] = sp[t];
            }
            __syncthreads();
            if (tid < 128) {
                float s = 0.f;
#pragma unroll
                for (int g = 0; g < 16; g++) s += sred[g * 128 + tid];
                ssc[tid] = s * invS;
            }
            __syncthreads();
            if (tid < 128) {
                float a = blv[(l + 1) * 128 + tid];
                for (int k4 = 0; k4 < 32; k4++)
                    a += dot4(*(const float4*)(ssc + k4 * 4), WlP[k4 * 384 + (l + 1) * 128 + tid]);
                sbase[tid] = a;
            }
            __syncthreads();
        }
    }
    __syncthreads();

    // ================= pool: slice means, 4-channel vectorized =================
    if (tid < 768) {
        int c4 = tid & 31, p = tid >> 5;
        int axis = p >> 3, idx = p & 7;
        float4 sum = {0.f, 0.f, 0.f, 0.f};
        for (int t = 0; t < 64; t++) {
            int node;
            if (axis == 0)      node = idx * 64 + t;
            else if (axis == 1) node = (t >> 3) * 64 + idx * 8 + (t & 7);
            else                node = t * 8 + idx;
            uint2 pk = *(const uint2*)(X + node * 136 + c4 * 4);
            sum.x += __uint_as_float(pk.x << 16);
            sum.y += __uint_as_float(pk.x & 0xffff0000u);
            sum.z += __uint_as_float(pk.y << 16);
            sum.w += __uint_as_float(pk.y & 0xffff0000u);
        }
        float4 o;
        o.x = sum.x * (1.f / 64.f); o.y = sum.y * (1.f / 64.f);
        o.z = sum.z * (1.f / 64.f); o.w = sum.w * (1.f / 64.f);
        *(float4*)(out + (size_t)b * 26 * Cc + p * Cc + c4 * 4) = o;
    }
}

// ---------------------------------------------------------------------------
// k_tf3: transformer with bf16 MFMA GEMMs (unchanged)
// ---------------------------------------------------------------------------
__global__ __launch_bounds__(256) void k_tf3(
    const int* __restrict__ xx, const float* __restrict__ ss,
    const ushort* __restrict__ WactB, const float* __restrict__ bact,
    const ushort* __restrict__ WqkvB, const float* __restrict__ bqkv,
    const ushort* __restrict__ WoB, const float* __restrict__ bo,
    const float* __restrict__ ln1g, const float* __restrict__ ln1b,
    const float* __restrict__ ln2g, const float* __restrict__ ln2b,
    const ushort* __restrict__ W1B, const float* __restrict__ b1v,
    const ushort* __restrict__ W2B, const float* __restrict__ b2v,
    const float* __restrict__ Wsc, const float* __restrict__ bsc,
    float* __restrict__ out)
{
    __shared__ float  As[TT * 132];
    __shared__ float  Qs[TT * 388];
    __shared__ ushort Ab[16 * 136];
    __shared__ ushort Hs[16 * 136];
    __shared__ ushort Fs[16 * 520];
    __shared__ float  Att[60 * 16];
    __shared__ float  mu_s[TT], rs_s[TT];

    int b = blockIdx.x, tid = threadIdx.x;
    int wv = tid >> 6, lane = tid & 63;
    int ml = lane & 15, quad = lane >> 4;

    const int* xa = xx + (size_t)b * Tsz * S3 + S3;
    for (int f = tid; f < TT * 512; f += 256) {
        int t = f >> 9, s = f & 511;
        Fs[t * 520 + s] = f2bu((float)xa[t * 512 + s]);
    }
    __syncthreads();

    {
        f32x4 acc[2];
#pragma unroll
        for (int i = 0; i < 2; i++) acc[i] = (f32x4){0.f, 0.f, 0.f, 0.f};
        const ushort* ar = Fs + ml * 520 + quad * 8;
        for (int ks = 0; ks < 16; ks++) {
            short8 a = *(const short8*)(ar + ks * 32);
#pragma unroll
            for (int i = 0; i < 2; i++) {
                int n0 = (wv * 2 + i) * 16;
                short8 bfr = *(const short8*)(WactB + (size_t)(n0 + ml) * 512 + quad * 8 + ks * 32);
                acc[i] = __builtin_amdgcn_mfma_f32_16x16x32_bf16(a, bfr, acc[i], 0, 0, 0);
            }
        }
#pragma unroll
        for (int i = 0; i < 2; i++) {
            int col = (wv * 2 + i) * 16 + ml;
            float bb = bact[col];
#pragma unroll
            for (int r = 0; r < 4; r++) {
                int row = quad * 4 + r;
                if (row < TT) As[row * 132 + col] = acc[i][r] + bb;
            }
        }
    }
    __syncthreads();

    for (int l = 0; l < 2; l++) {
        const float* bq  = bqkv + l * 384;
        const float* bol = bo + l * 128;
        const float* g1  = ln1g + l * 128; const float* be1 = ln1b + l * 128;
        const float* g2  = ln2g + l * 128; const float* be2 = ln2b + l * 128;
        const float* b1l = b1v + l * 512;  const float* b2l = b2v + l * 128;

        for (int r = wv; r < TT; r += 4) {
            float2 v = *(const float2*)(As + r * 132 + lane * 2);
            float s = v.x + v.y, q = v.x * v.x + v.y * v.y;
            for (int off = 32; off; off >>= 1) {
                s += __shfl_xor(s, off, 64);
                q += __shfl_xor(q, off, 64);
            }
            if (lane == 0) {
                float mu = s * (1.f / 128.f);
                mu_s[r] = mu;
                rs_s[r] = rsqrtf(q * (1.f / 128.f) - mu * mu + EPSv);
            }
        }
        __syncthreads();
        for (int f = tid; f < TT * 64; f += 256) {
            int t = f >> 6, cp = f & 63;
            float mu = mu_s[t], rs = rs_s[t];
            float x0 = (As[t * 132 + 2 * cp]     - mu) * rs * g1[2 * cp]     + be1[2 * cp];
            float x1 = (As[t * 132 + 2 * cp + 1] - mu) * rs * g1[2 * cp + 1] + be1[2 * cp + 1];
            ((unsigned*)(Ab + t * 136))[cp] = packbf(x0, x1);
        }
        __syncthreads();

        {
            short8 a[4];
            const ushort* ar = Ab + ml * 136 + quad * 8;
#pragma unroll
            for (int ks = 0; ks < 4; ks++) a[ks] = *(const short8*)(ar + ks * 32);
#pragma unroll
            for (int i = 0; i < 6; i++) {
                int n0 = (wv * 6 + i) * 16;
                f32x4 acc = (f32x4){0.f, 0.f, 0.f, 0.f};
                const ushort* wb = WqkvB + (size_t)(l * 384 + n0 + ml) * 128 + quad * 8;
#pragma unroll
                for (int ks = 0; ks < 4; ks++) {
                    short8 bfr = *(const short8*)(wb + ks * 32);
                    acc = __builtin_amdgcn_mfma_f32_16x16x32_bf16(a[ks], bfr, acc, 0, 0, 0);
                }
                int col = n0 + ml;
                float bb = bq[col];
#pragma unroll
                for (int r = 0; r < 4; r++) {
                    int row = quad * 4 + r;
                    if (row < TT) Qs[row * 388 + col] = acc[r] + bb;
                }
            }
        }
        __syncthreads();

        if (tid < 60) {
            int h = tid / 15, tq = tid % 15;
            const float* qp = Qs + tq * 388 + h * 32;
            float sc[TT];
            float mx = -1e30f;
#pragma unroll
            for (int tk = 0; tk < TT; tk++) {
                const float* kp = Qs + tk * 388 + 128 + h * 32;
                float d = 0.f;
#pragma unroll
                for (int u = 0; u < 32; u += 4)
                    d += dot4(*(const float4*)(qp + u), *(const float4*)(kp + u));
                d *= 0.17677669529663689f;
                sc[tk] = d; mx = fmaxf(mx, d);
            }
            float sum = 0.f;
#pragma unroll
            for (int tk = 0; tk < TT; tk++) { float e = __expf(sc[tk] - mx); sc[tk] = e; sum += e; }
            float r = 1.f / sum;
#pragma unroll
            for (int tk = 0; tk < TT; tk++) Att[tid * 16 + tk] = sc[tk] * r;
        }
        __syncthreads();

        for (int f = tid; f < TT * 64; f += 256) {
            int t = f >> 6, cp = f & 63;
            int c0 = 2 * cp, c1 = 2 * cp + 1;
            int h = c0 >> 5;
            const float* ap = Att + (h * 15 + t) * 16;
            const float* vp = Qs + 256;
            float a0 = 0.f, a1 = 0.f;
#pragma unroll
            for (int tk = 0; tk < TT; tk++) {
                float w = ap[tk];
                a0 += w * vp[tk * 388 + c0];
                a1 += w * vp[tk * 388 + c1];
            }
            ((unsigned*)(Hs + t * 136))[cp] = packbf(a0, a1);
        }
        __syncthreads();

        {
            short8 a[4];
            const ushort* ar = Hs + ml * 136 + quad * 8;
#pragma unroll
            for (int ks = 0; ks < 4; ks++) a[ks] = *(const short8*)(ar + ks * 32);
#pragma unroll
            for (int i = 0; i < 2; i++) {
                int n0 = (wv * 2 + i) * 16;
                f32x4 acc = (f32x4){0.f, 0.f, 0.f, 0.f};
                const ushort* wb = WoB + (size_t)(l * 128 + n0 + ml) * 128 + quad * 8;
#pragma unroll
                for (int ks = 0; ks < 4; ks++) {
                    short8 bfr = *(const short8*)(wb + ks * 32);
                    acc = __builtin_amdgcn_mfma_f32_16x16x32_bf16(a[ks], bfr, acc, 0, 0, 0);
                }
                int col = n0 + ml;
                float bb = bol[col];
#pragma unroll
                for (int r = 0; r < 4; r++) {
                    int row = quad * 4 + r;
                    if (row < TT) As[row * 132 + col] += acc[r] + bb;
                }
            }
        }
        __syncthreads();

        for (int r = wv; r < TT; r += 4) {
            float2 v = *(const float2*)(As + r * 132 + lane * 2);
            float s = v.x + v.y, q = v.x * v.x + v.y * v.y;
            for (int off = 32; off; off >>= 1) {
                s += __shfl_xor(s, off, 64);
                q += __shfl_xor(q, off, 64);
            }
            if (lane == 0) {
                float mu = s * (1.f / 128.f);
                mu_s[r] = mu;
                rs_s[r] = rsqrtf(q * (1.f / 128.f) - mu * mu + EPSv);
            }
        }
        __syncthreads();
        for (int f = tid; f < TT * 64; f += 256) {
            int t = f >> 6, cp = f & 63;
            float mu = mu_s[t], rs = rs_s[t];
            float x0 = (As[t * 132 + 2 * cp]     - mu) * rs * g2[2 * cp]     + be2[2 * cp];
            float x1 = (As[t * 132 + 2 * cp + 1] - mu) * rs * g2[2 * cp + 1] + be2[2 * cp + 1];
            ((unsigned*)(Ab + t * 136))[cp] = packbf(x0, x1);
        }
        __syncthreads();

        {
            short8 a[4];
            const ushort* ar = Ab + ml * 136 + quad * 8;
#pragma unroll
            for (int ks = 0; ks < 4; ks++) a[ks] = *(const short8*)(ar + ks * 32);
#pragma unroll
            for (int i = 0; i < 8; i++) {
                int n0 = (wv * 8 + i) * 16;
                f32x4 acc = (f32x4){0.f, 0.f, 0.f, 0.f};
                const ushort* wb = W1B + (size_t)(l * 512 + n0 + ml) * 128 + quad * 8;
#pragma unroll
                for (int ks = 0; ks < 4; ks++) {
                    short8 bfr = *(const short8*)(wb + ks * 32);
                    acc = __builtin_amdgcn_mfma_f32_16x16x32_bf16(a[ks], bfr, acc, 0, 0, 0);
                }
                int col = n0 + ml;
                float bb = b1l[col];
#pragma unroll
                for (int r = 0; r < 4; r++) {
                    int row = quad * 4 + r;
                    if (row < TT) Fs[row * 520 + col] = f2bu(fmaxf(acc[r] + bb, 0.f));
                }
            }
        }
        __syncthreads();

        {
            f32x4 acc[2];
#pragma unroll
            for (int i = 0; i < 2; i++) acc[i] = (f32x4){0.f, 0.f, 0.f, 0.f};
            const ushort* ar = Fs + ml * 520 + quad * 8;
            for (int ks = 0; ks < 16; ks++) {
                short8 a = *(const short8*)(ar + ks * 32);
#pragma unroll
                for (int i = 0; i < 2; i++) {
                    int n0 = (wv * 2 + i) * 16;
                    short8 bfr = *(const short8*)(W2B + (size_t)(l * 128 + n0 + ml) * 512 + quad * 8 + ks * 32);
                    acc[i] = __builtin_amdgcn_mfma_f32_16x16x32_bf16(a, bfr, acc[i], 0, 0, 0);
                }
            }
#pragma unroll
            for (int i = 0; i < 2; i++) {
                int col = (wv * 2 + i) * 16 + ml;
                float bb = b2l[col];
#pragma unroll
                for (int r = 0; r < 4; r++) {
                    int row = quad * 4 + r;
                    if (row < TT) As[row * 132 + col] += acc[i][r] + bb;
                }
            }
        }
        __syncthreads();
    }

    if (tid < 128) {
        float s = 0.f;
#pragma unroll
        for (int t = 0; t < TT; t++) s += As[t * 132 + tid];
        out[(size_t)b * 26 * Cc + 24 * Cc + tid] = s * (1.f / 15.f);
    } else if (tid < 256) {
        int co = tid - 128;
        float v = ss[b] * Wsc[co] + bsc[co];
        out[(size_t)b * 26 * Cc + 25 * Cc + co] = fmaxf(v, 0.f);
    }
}

// ---------------------------------------------------------------------------
extern "C" void kernel_launch(void* const* d_in, const int* in_sizes, int n_in,
                              void* d_out, int out_size, void* d_ws, size_t ws_size,
                              hipStream_t stream)
{
    (void)in_sizes; (void)n_in; (void)out_size; (void)ws_size;
    const int*   xx   = (const int*)d_in[0];
    const float* ss   = (const float*)d_in[1];
    const float* Win  = (const float*)d_in[2];
    const float* b_in = (const float*)d_in[3];
    const float* Wl   = (const float*)d_in[4];
    const float* bl   = (const float*)d_in[5];
    const float* Wr   = (const float*)d_in[6];
    const float* lng  = (const float*)d_in[7];
    const float* lnb  = (const float*)d_in[8];
    const float* Wqkv = (const float*)d_in[9];
    const float* bqkv = (const float*)d_in[10];
    const float* Wo   = (const float*)d_in[11];
    const float* bo   = (const float*)d_in[12];
    const float* ln1g = (const float*)d_in[13];
    const float* ln1b = (const float*)d_in[14];
    const float* ln2g = (const float*)d_in[15];
    const float* ln2b = (const float*)d_in[16];
    const float* W1   = (const float*)d_in[17];
    const float* b1   = (const float*)d_in[18];
    const float* W2   = (const float*)d_in[19];
    const float* b2   = (const float*)d_in[20];
    const float* Wact = (const float*)d_in[21];
    const float* bact = (const float*)d_in[22];
    const float* Wsc  = (const float*)d_in[23];
    const float* bsc  = (const float*)d_in[24];
    float* out = (float*)d_out;

    char* ws = (char*)d_ws;
    size_t off = 0;
    float* WlT  = (float*)(ws + off); off += 384 * 128 * 4;
    ushort* dbuf  = (ushort*)(ws + off); off += (size_t)Bsz * 3 * 32 * 512 * 2;  // 50.3 MB
    ushort* WactB = (ushort*)(ws + off); off += 128 * 512 * 2;
    ushort* WqkvB = (ushort*)(ws + off); off += 768 * 128 * 2;
    ushort* WoB   = (ushort*)(ws + off); off += 256 * 128 * 2;
    ushort* W1B   = (ushort*)(ws + off); off += 1024 * 128 * 2;
    ushort* W2B   = (ushort*)(ws + off); off += 256 * 512 * 2;

    k_tpack<<<dim3(4, 12), 256, 0, stream>>>(Wl, WlT, 384, 128);
    k_cvt<<<(128 * 512 / 4 + 255) / 256, 256, 0, stream>>>(Wact, WactB, 128 * 512 / 4);
    k_cvt<<<(768 * 128 / 4 + 255) / 256, 256, 0, stream>>>(Wqkv, WqkvB, 768 * 128 / 4);
    k_cvt<<<(256 * 128 / 4 + 255) / 256, 256, 0, stream>>>(Wo,   WoB,   256 * 128 / 4);
    k_cvt<<<(1024 * 128 / 4 + 255) / 256, 256, 0, stream>>>(W1,  W1B,  1024 * 128 / 4);
    k_cvt<<<(256 * 512 / 4 + 255) / 256, 256, 0, stream>>>(W2,   W2B,   256 * 512 / 4);

    k_dwall<<<dim3(Bsz, 3), 256, 0, stream>>>(xx, Wl, Wr, dbuf);

    k_torso<<<Bsz, 1024, 0, stream>>>(xx, ss, Win, b_in, dbuf,
                                      (const float4*)WlT, bl, lng, lnb, out);

    k_tf3<<<Bsz, 256, 0, stream>>>(xx, ss,
                                   WactB, bact, WqkvB, bqkv, WoB, bo,
                                   ln1g, ln1b, ln2g, ln2b,
                                   W1B, b1, W2B, b2,
                                   Wsc, bsc, out);
}